// Round 1
// baseline (339.485 us; speedup 1.0000x reference)
//
#include <hip/hip_runtime.h>
#include <hip/hip_bf16.h>

#define DIM 768
#define NHEADS 12
#define HD 64
#define NTOK 197
#define BATCH 64
#define NTOKENS (BATCH*NTOK)          // 12608
#define NPAIR (NTOK*NTOK)             // 38809
#define QK_SCALE 0.125f               // 64^-0.5

typedef short bf16x8 __attribute__((ext_vector_type(8)));
typedef float f32x4 __attribute__((ext_vector_type(4)));

#define MFMA(a,b,c) __builtin_amdgcn_mfma_f32_16x16x32_bf16(a,b,c,0,0,0)

__device__ __forceinline__ unsigned short f2bf(float f) {
    union { float f; unsigned u; } v; v.f = f;
    unsigned r = v.u + 0x7FFFu + ((v.u >> 16) & 1u);
    return (unsigned short)(r >> 16);
}

// ---------------- bias precompute: biasm[h][i][j] = rpb[rel[i*197+j]*12 + h]
__global__ __launch_bounds__(256) void bias_pre(const float* __restrict__ rpb,
                                                const int* __restrict__ rel,
                                                float* __restrict__ biasm) {
    int t = blockIdx.x * 256 + threadIdx.x;
    if (t >= NHEADS * NPAIR) return;
    int h = t / NPAIR, p = t - h * NPAIR;
    biasm[t] = rpb[rel[p] * NHEADS + h];
}

// ---------------- GEMM1: qkv = x @ qkv_w^T (+bias), scatter to q/k/v bf16 [B,H,N,d]
#define BM 128
#define BN 128
#define BK 32
#define APITCH 40   // pitch 40 elems = 80B: 16B-aligned rows, 2-way bank alias (free)

__global__ __launch_bounds__(256) void gemm_qkv(
    const float* __restrict__ X, const float* __restrict__ W,
    const float* __restrict__ qbias, const float* __restrict__ vbias,
    unsigned short* __restrict__ Qb, unsigned short* __restrict__ Kb,
    unsigned short* __restrict__ Vb)
{
    __shared__ __attribute__((aligned(16))) unsigned short As[BM][APITCH];
    __shared__ __attribute__((aligned(16))) unsigned short Bs[BN][APITCH];
    int tid = threadIdx.x;
    int lane = tid & 63, wid = tid >> 6;
    int m0 = blockIdx.x * BM;
    int n0 = blockIdx.y * BN;
    int wm = (wid >> 1) * 64, wn = (wid & 1) * 64;

    f32x4 acc[4][4];
    #pragma unroll
    for (int i = 0; i < 4; ++i)
        #pragma unroll
        for (int j = 0; j < 4; ++j) acc[i][j] = (f32x4){0.f,0.f,0.f,0.f};

    for (int k0 = 0; k0 < DIM; k0 += BK) {
        __syncthreads();
        // stage A (x fp32 -> bf16): 128 rows x 8 float4-chunks = 1024 chunks
        #pragma unroll
        for (int t = 0; t < 4; ++t) {
            int c = t * 256 + tid;
            int row = c >> 3, kc = c & 7;
            int gr = m0 + row;
            float4 v = make_float4(0.f, 0.f, 0.f, 0.f);
            if (gr < NTOKENS) v = ((const float4*)(X + (size_t)gr * DIM + k0))[kc];
            union { unsigned short s[4]; unsigned long long u; } pk;
            pk.s[0] = f2bf(v.x); pk.s[1] = f2bf(v.y);
            pk.s[2] = f2bf(v.z); pk.s[3] = f2bf(v.w);
            *(unsigned long long*)&As[row][kc * 4] = pk.u;
        }
        // stage B (qkv_w fp32 -> bf16), rows always in-bounds (N=2304 = 18*128)
        #pragma unroll
        for (int t = 0; t < 4; ++t) {
            int c = t * 256 + tid;
            int row = c >> 3, kc = c & 7;
            float4 v = ((const float4*)(W + (size_t)(n0 + row) * DIM + k0))[kc];
            union { unsigned short s[4]; unsigned long long u; } pk;
            pk.s[0] = f2bf(v.x); pk.s[1] = f2bf(v.y);
            pk.s[2] = f2bf(v.z); pk.s[3] = f2bf(v.w);
            *(unsigned long long*)&Bs[row][kc * 4] = pk.u;
        }
        __syncthreads();

        bf16x8 af[4], bfr[4];
        #pragma unroll
        for (int i = 0; i < 4; ++i)
            af[i] = *(bf16x8*)&As[wm + i * 16 + (lane & 15)][(lane >> 4) * 8];
        #pragma unroll
        for (int j = 0; j < 4; ++j)
            bfr[j] = *(bf16x8*)&Bs[wn + j * 16 + (lane & 15)][(lane >> 4) * 8];
        #pragma unroll
        for (int i = 0; i < 4; ++i)
            #pragma unroll
            for (int j = 0; j < 4; ++j)
                acc[i][j] = MFMA(af[i], bfr[j], acc[i][j]);
    }

    // epilogue: bias + scale + scatter to q/k/v [B,H,N,d]
    #pragma unroll
    for (int j = 0; j < 4; ++j) {
        int col = n0 + wn + j * 16 + (lane & 15);
        int which = col / DIM;
        int rem = col - which * DIM;
        int hh = rem >> 6, dd = rem & 63;
        float bv = (which == 0) ? qbias[rem] : (which == 2 ? vbias[rem] : 0.f);
        float scl = (which == 0) ? QK_SCALE : 1.f;
        unsigned short* dst = (which == 0) ? Qb : (which == 1 ? Kb : Vb);
        #pragma unroll
        for (int i = 0; i < 4; ++i) {
            #pragma unroll
            for (int r = 0; r < 4; ++r) {
                int row = m0 + wm + i * 16 + (lane >> 4) * 4 + r;
                if (row < NTOKENS) {
                    int b = row / NTOK, n = row - b * NTOK;
                    float val = (acc[i][j][r] + bv) * scl;
                    dst[((size_t)(b * NHEADS + hh) * NTOK + n) * HD + dd] = f2bf(val);
                }
            }
        }
    }
}

// ---------------- fused attention: one block per (q-tile, h, b); 4 waves x 16 q-rows
#define KPITCH 72    // 144B rows: 16B-aligned, 2-way bank alias
#define VPITCH 232   // 464B rows: 16B-aligned, 2-way bank alias; covers 224 padded keys

__global__ __launch_bounds__(256) void attn(
    const unsigned short* __restrict__ Q, const unsigned short* __restrict__ K,
    const unsigned short* __restrict__ V, const float* __restrict__ biasm,
    unsigned short* __restrict__ O)
{
    __shared__ __attribute__((aligned(16))) unsigned short Kl[208][KPITCH];
    __shared__ __attribute__((aligned(16))) unsigned short VT[64][VPITCH];
    __shared__ __attribute__((aligned(16))) unsigned short Pl[4][16][VPITCH];

    int tid = threadIdx.x, lane = tid & 63, wid = tid >> 6;
    int qt = blockIdx.x, h = blockIdx.y, b = blockIdx.z;
    size_t base = (size_t)(b * NHEADS + h) * NTOK * HD;

    // phase 0: zero VT and Pl (padding regions must be 0, not NaN-garbage)
    {
        f32x4* vtz = (f32x4*)&VT[0][0];
        f32x4* plz = (f32x4*)&Pl[0][0][0];
        const int nchunks = 64 * VPITCH * 2 / 16;   // 1856
        #pragma unroll
        for (int t = 0; t < 8; ++t) {
            int c = t * 256 + tid;
            if (c < nchunks) { vtz[c] = (f32x4){0.f,0.f,0.f,0.f}; plz[c] = (f32x4){0.f,0.f,0.f,0.f}; }
        }
    }
    __syncthreads();

    // phase 1: stage K rows and V transposed
    #pragma unroll
    for (int t = 0; t < 7; ++t) {
        int c = t * 256 + tid;
        if (c < NTOK * 8) {
            int row = c >> 3, kc = c & 7;
            bf16x8 kv = *(const bf16x8*)(K + base + (size_t)row * HD + kc * 8);
            *(bf16x8*)&Kl[row][kc * 8] = kv;
            bf16x8 vv = *(const bf16x8*)(V + base + (size_t)row * HD + kc * 8);
            #pragma unroll
            for (int j = 0; j < 8; ++j) VT[kc * 8 + j][row] = (unsigned short)vv[j];
        }
    }
    __syncthreads();

    // Q fragments (from global; small, L2-resident)
    int qrow_g = qt * 64 + wid * 16 + (lane & 15);
    int qsrc = qrow_g < NTOK ? qrow_g : (NTOK - 1);
    bf16x8 aq[2];
    #pragma unroll
    for (int ks = 0; ks < 2; ++ks)
        aq[ks] = *(const bf16x8*)(Q + base + (size_t)qsrc * HD + ks * 32 + (lane >> 4) * 8);

    // S = Q K^T  (13 col-tiles of 16 keys)
    f32x4 sa[13];
    #pragma unroll
    for (int t = 0; t < 13; ++t) sa[t] = (f32x4){0.f,0.f,0.f,0.f};
    #pragma unroll
    for (int t = 0; t < 13; ++t) {
        #pragma unroll
        for (int ks = 0; ks < 2; ++ks) {
            bf16x8 bk = *(bf16x8*)&Kl[t * 16 + (lane & 15)][ks * 32 + (lane >> 4) * 8];
            sa[t] = MFMA(aq[ks], bk, sa[t]);
        }
    }

    // bias + mask + softmax + write P (bf16) to LDS
    int rbase = qt * 64 + wid * 16 + (lane >> 4) * 4;
    #pragma unroll
    for (int r = 0; r < 4; ++r) {
        int row_g = rbase + r;
        int rowc = row_g < NTOK ? row_g : (NTOK - 1);
        #pragma unroll
        for (int t = 0; t < 13; ++t) {
            int col = t * 16 + (lane & 15);
            if (col < NTOK) sa[t][r] += biasm[h * NPAIR + rowc * NTOK + col];
            else            sa[t][r] = -1e30f;
        }
        float mx = sa[0][r];
        #pragma unroll
        for (int t = 1; t < 13; ++t) mx = fmaxf(mx, sa[t][r]);
        #pragma unroll
        for (int m = 1; m < 16; m <<= 1) mx = fmaxf(mx, __shfl_xor(mx, m));
        float sum = 0.f;
        #pragma unroll
        for (int t = 0; t < 13; ++t) {
            float e = __expf(sa[t][r] - mx);
            sa[t][r] = e; sum += e;
        }
        #pragma unroll
        for (int m = 1; m < 16; m <<= 1) sum += __shfl_xor(sum, m);
        float inv = 1.f / sum;
        #pragma unroll
        for (int t = 0; t < 13; ++t)
            Pl[wid][(lane >> 4) * 4 + r][t * 16 + (lane & 15)] = f2bf(sa[t][r] * inv);
    }

    // O = P V  (keys padded to 224; pads are zero)
    f32x4 oa[4];
    #pragma unroll
    for (int dt = 0; dt < 4; ++dt) oa[dt] = (f32x4){0.f,0.f,0.f,0.f};
    #pragma unroll
    for (int ks = 0; ks < 7; ++ks) {
        bf16x8 ap = *(bf16x8*)&Pl[wid][lane & 15][ks * 32 + (lane >> 4) * 8];
        #pragma unroll
        for (int dt = 0; dt < 4; ++dt) {
            bf16x8 bv = *(bf16x8*)&VT[dt * 16 + (lane & 15)][ks * 32 + (lane >> 4) * 8];
            oa[dt] = MFMA(ap, bv, oa[dt]);
        }
    }
    #pragma unroll
    for (int dt = 0; dt < 4; ++dt) {
        #pragma unroll
        for (int r = 0; r < 4; ++r) {
            int row_g = rbase + r;
            if (row_g < NTOK) {
                int col = dt * 16 + (lane & 15);
                O[base + (size_t)row_g * HD + col] = f2bf(oa[dt][r]);
            }
        }
    }
}

// ---------------- GEMM2: out = O @ proj_w^T + proj_b  (fp32 out)
__global__ __launch_bounds__(256) void gemm_proj(
    const unsigned short* __restrict__ Ob, const float* __restrict__ W,
    const float* __restrict__ pbias, float* __restrict__ out)
{
    __shared__ __attribute__((aligned(16))) unsigned short As[BM][APITCH];
    __shared__ __attribute__((aligned(16))) unsigned short Bs[BN][APITCH];
    int tid = threadIdx.x;
    int lane = tid & 63, wid = tid >> 6;
    int m0 = blockIdx.x * BM;
    int n0 = blockIdx.y * BN;
    int wm = (wid >> 1) * 64, wn = (wid & 1) * 64;

    f32x4 acc[4][4];
    #pragma unroll
    for (int i = 0; i < 4; ++i)
        #pragma unroll
        for (int j = 0; j < 4; ++j) acc[i][j] = (f32x4){0.f,0.f,0.f,0.f};

    for (int k0 = 0; k0 < DIM; k0 += BK) {
        __syncthreads();
        // stage A from O [B,H,N,64] (bf16): 128 rows x 4 chunks of 8 elems
        #pragma unroll
        for (int t = 0; t < 2; ++t) {
            int c = t * 256 + tid;
            int row = c >> 2, kc = c & 3;
            int gr = m0 + row;
            int k = k0 + kc * 8;
            bf16x8 v = (bf16x8)(short)0;
            if (gr < NTOKENS) {
                int b = gr / NTOK, n = gr - b * NTOK;
                int hh = k >> 6, dd = k & 63;
                v = *(const bf16x8*)(Ob + ((size_t)(b * NHEADS + hh) * NTOK + n) * HD + dd);
            }
            *(bf16x8*)&As[row][kc * 8] = v;
        }
        // stage B (proj_w fp32 -> bf16), rows in-bounds (N=768 = 6*128)
        #pragma unroll
        for (int t = 0; t < 4; ++t) {
            int c = t * 256 + tid;
            int row = c >> 3, kc = c & 7;
            float4 v = ((const float4*)(W + (size_t)(n0 + row) * DIM + k0))[kc];
            union { unsigned short s[4]; unsigned long long u; } pk;
            pk.s[0] = f2bf(v.x); pk.s[1] = f2bf(v.y);
            pk.s[2] = f2bf(v.z); pk.s[3] = f2bf(v.w);
            *(unsigned long long*)&Bs[row][kc * 4] = pk.u;
        }
        __syncthreads();

        bf16x8 af[4], bfr[4];
        #pragma unroll
        for (int i = 0; i < 4; ++i)
            af[i] = *(bf16x8*)&As[wm + i * 16 + (lane & 15)][(lane >> 4) * 8];
        #pragma unroll
        for (int j = 0; j < 4; ++j)
            bfr[j] = *(bf16x8*)&Bs[wn + j * 16 + (lane & 15)][(lane >> 4) * 8];
        #pragma unroll
        for (int i = 0; i < 4; ++i)
            #pragma unroll
            for (int j = 0; j < 4; ++j)
                acc[i][j] = MFMA(af[i], bfr[j], acc[i][j]);
    }

    #pragma unroll
    for (int j = 0; j < 4; ++j) {
        int col = n0 + wn + j * 16 + (lane & 15);
        float bv = pbias[col];
        #pragma unroll
        for (int i = 0; i < 4; ++i) {
            #pragma unroll
            for (int r = 0; r < 4; ++r) {
                int row = m0 + wm + i * 16 + (lane >> 4) * 4 + r;
                if (row < NTOKENS)
                    out[(size_t)row * DIM + col] = acc[i][j][r] + bv;
            }
        }
    }
}

extern "C" void kernel_launch(void* const* d_in, const int* in_sizes, int n_in,
                              void* d_out, int out_size, void* d_ws, size_t ws_size,
                              hipStream_t stream) {
    const float* x      = (const float*)d_in[0];
    const float* qkv_w  = (const float*)d_in[1];
    const float* q_bias = (const float*)d_in[2];
    const float* v_bias = (const float*)d_in[3];
    const float* rpb    = (const float*)d_in[4];
    const float* proj_w = (const float*)d_in[5];
    const float* proj_b = (const float*)d_in[6];
    const int*   rel    = (const int*)d_in[7];
    float* out = (float*)d_out;

    const size_t NELEM = (size_t)NTOKENS * DIM;      // 9,682,944
    unsigned short* Qb = (unsigned short*)d_ws;
    unsigned short* Kb = Qb + NELEM;
    unsigned short* Vb = Kb + NELEM;
    unsigned short* Ob = Vb + NELEM;
    float* biasm = (float*)(Ob + NELEM);             // 465,708 floats

    bias_pre<<<(NHEADS * NPAIR + 255) / 256, 256, 0, stream>>>(rpb, rel, biasm);

    dim3 g1((NTOKENS + BM - 1) / BM, 3 * DIM / BN);  // 99 x 18
    gemm_qkv<<<g1, 256, 0, stream>>>(x, qkv_w, q_bias, v_bias, Qb, Kb, Vb);

    dim3 ga(4, NHEADS, BATCH);                        // 4 q-tiles x 12 x 64
    attn<<<ga, 256, 0, stream>>>(Qb, Kb, Vb, biasm, Ob);

    dim3 g2((NTOKENS + BM - 1) / BM, DIM / BN);       // 99 x 6
    gemm_proj<<<g2, 256, 0, stream>>>(Ob, proj_w, proj_b, out);
}

// Round 2
// 276.523 us; speedup vs baseline: 1.2277x; 1.2277x over previous
//
#include <hip/hip_runtime.h>
#include <hip/hip_bf16.h>

#define DIM 768
#define NHEADS 12
#define HD 64
#define NTOK 197
#define BATCH 64
#define NTOKENS (BATCH*NTOK)          // 12608
#define NPAIR (NTOK*NTOK)             // 38809
#define QK_SCALE 0.125f               // 64^-0.5

typedef short bf16x8 __attribute__((ext_vector_type(8)));
typedef float f32x4 __attribute__((ext_vector_type(4)));

#define MFMA(a,b,c) __builtin_amdgcn_mfma_f32_16x16x32_bf16(a,b,c,0,0,0)

__device__ __forceinline__ unsigned short f2bf(float f) {
    union { float f; unsigned u; } v; v.f = f;
    unsigned r = v.u + 0x7FFFu + ((v.u >> 16) & 1u);
    return (unsigned short)(r >> 16);
}

__device__ __forceinline__ void gload16(const unsigned short* g, unsigned short* l) {
    __builtin_amdgcn_global_load_lds(
        (const __attribute__((address_space(1))) void*)g,
        (__attribute__((address_space(3))) void*)l, 16, 0, 0);
}

// ---------------- fp32 -> bf16 bulk convert (8 elems/thread)
__global__ __launch_bounds__(256) void to_bf16(const float* __restrict__ s,
                                               unsigned short* __restrict__ d, int n8) {
    int t = blockIdx.x * 256 + threadIdx.x;
    if (t >= n8) return;
    float4 a = ((const float4*)s)[t * 2], b = ((const float4*)s)[t * 2 + 1];
    union { unsigned short u[8]; bf16x8 v; } p;
    p.u[0] = f2bf(a.x); p.u[1] = f2bf(a.y); p.u[2] = f2bf(a.z); p.u[3] = f2bf(a.w);
    p.u[4] = f2bf(b.x); p.u[5] = f2bf(b.y); p.u[6] = f2bf(b.z); p.u[7] = f2bf(b.w);
    ((bf16x8*)d)[t] = p.v;
}

// ---------------- bias precompute: biasm[h][i][j] = rpb[rel[i*197+j]*12 + h]
__global__ __launch_bounds__(256) void bias_pre(const float* __restrict__ rpb,
                                                const int* __restrict__ rel,
                                                float* __restrict__ biasm) {
    int t = blockIdx.x * 256 + threadIdx.x;
    if (t >= NHEADS * NPAIR) return;
    int h = t / NPAIR, p = t - h * NPAIR;
    biasm[t] = rpb[rel[p] * NHEADS + h];
}

// ---------------- GEMM1: qkv = Xb @ Wb^T (+bias), scatter to q/k/v bf16 [B,H,N,d]
// 128x128 tile, BK=64, 4 waves, global_load_lds w=16, XOR-swizzled LDS (T2/rule21)
__global__ __launch_bounds__(256) void gemm_qkv(
    const unsigned short* __restrict__ Xb, const unsigned short* __restrict__ Wb,
    const float* __restrict__ qbias, const float* __restrict__ vbias,
    unsigned short* __restrict__ Qb, unsigned short* __restrict__ Kb,
    unsigned short* __restrict__ Vb)
{
    __shared__ __attribute__((aligned(16))) unsigned short As[128 * 64];
    __shared__ __attribute__((aligned(16))) unsigned short Bs[128 * 64];
    int tid = threadIdx.x, lane = tid & 63, wid = tid >> 6;
    int m0 = blockIdx.x * 128, n0 = blockIdx.y * 128;
    int wm = (wid >> 1) * 64, wn = (wid & 1) * 64;

    // staging source bases (per lane). LDS dest is linear; source is
    // inverse-swizzled so that LDS[row][slot] = global[row][slot ^ (row&7)].
    size_t abase[4], bbase[4];
    unsigned short *alds[4], *blds[4];
    #pragma unroll
    for (int i = 0; i < 4; ++i) {
        int chunk = i * 4 + wid;
        int row = chunk * 8 + (lane >> 3);
        int slot = (lane & 7) ^ (row & 7);
        int ar = m0 + row; if (ar >= NTOKENS) ar = NTOKENS - 1;
        abase[i] = (size_t)ar * DIM + slot * 8;
        bbase[i] = (size_t)(n0 + row) * DIM + slot * 8;
        alds[i] = &As[chunk * 512];
        blds[i] = &Bs[chunk * 512];
    }
    int r15 = lane & 15, hi = lane >> 4, sx = lane & 7;
    int s0 = (hi ^ sx) * 8, s1 = ((hi + 4) ^ sx) * 8;
    int arow[4], brow[4];
    #pragma unroll
    for (int i = 0; i < 4; ++i) {
        arow[i] = (wm + i * 16 + r15) * 64;
        brow[i] = (wn + i * 16 + r15) * 64;
    }

    f32x4 acc[4][4];
    #pragma unroll
    for (int i = 0; i < 4; ++i)
        #pragma unroll
        for (int j = 0; j < 4; ++j) acc[i][j] = (f32x4){0.f, 0.f, 0.f, 0.f};

    for (int k0 = 0; k0 < DIM; k0 += 64) {
        __syncthreads();                        // prev tile's reads done
        #pragma unroll
        for (int i = 0; i < 4; ++i) {
            gload16(Xb + abase[i] + k0, alds[i]);
            gload16(Wb + bbase[i] + k0, blds[i]);
        }
        __syncthreads();                        // drains vmcnt(0): tile ready
        #pragma unroll
        for (int ks = 0; ks < 2; ++ks) {
            int so = ks ? s1 : s0;
            bf16x8 af[4], bw[4];
            #pragma unroll
            for (int i = 0; i < 4; ++i) af[i] = *(bf16x8*)&As[arow[i] + so];
            #pragma unroll
            for (int j = 0; j < 4; ++j) bw[j] = *(bf16x8*)&Bs[brow[j] + so];
            #pragma unroll
            for (int i = 0; i < 4; ++i)
                #pragma unroll
                for (int j = 0; j < 4; ++j)
                    acc[i][j] = MFMA(af[i], bw[j], acc[i][j]);
        }
    }

    // epilogue: bias + scale + scatter to q/k/v [B,H,N,d]
    int which = n0 / DIM;                       // uniform: 0=Q 1=K 2=V
    unsigned short* dst = which == 0 ? Qb : (which == 1 ? Kb : Vb);
    float scl = which == 0 ? QK_SCALE : 1.f;
    int ncol0 = n0 - which * DIM;
    #pragma unroll
    for (int j = 0; j < 4; ++j) {
        int col = ncol0 + wn + j * 16 + r15;
        int hh = col >> 6, dd = col & 63;
        float bv = (which == 0) ? qbias[col] : (which == 2 ? vbias[col] : 0.f);
        #pragma unroll
        for (int i = 0; i < 4; ++i) {
            #pragma unroll
            for (int r = 0; r < 4; ++r) {
                int row = m0 + wm + i * 16 + hi * 4 + r;
                if (row < NTOKENS) {
                    int b = row / NTOK, n = row - b * NTOK;
                    float val = (acc[i][j][r] + bv) * scl;
                    dst[((size_t)(b * NHEADS + hh) * NTOK + n) * HD + dd] = f2bf(val);
                }
            }
        }
    }
}

// ---------------- fused attention: one block per (q-tile, h, b); 4 waves x 16 q-rows
#define KPITCH 72
#define VPITCH 232

__global__ __launch_bounds__(256) void attn(
    const unsigned short* __restrict__ Q, const unsigned short* __restrict__ K,
    const unsigned short* __restrict__ V, const float* __restrict__ biasm,
    unsigned short* __restrict__ O)
{
    __shared__ __attribute__((aligned(16))) unsigned short Kl[208][KPITCH];
    __shared__ __attribute__((aligned(16))) unsigned short VT[64][VPITCH];
    __shared__ __attribute__((aligned(16))) unsigned short Pl[4][16][VPITCH];

    int tid = threadIdx.x, lane = tid & 63, wid = tid >> 6;
    int qt = blockIdx.x, h = blockIdx.y, b = blockIdx.z;
    size_t base = (size_t)(b * NHEADS + h) * NTOK * HD;

    {
        f32x4* vtz = (f32x4*)&VT[0][0];
        f32x4* plz = (f32x4*)&Pl[0][0][0];
        const int nchunks = 64 * VPITCH * 2 / 16;
        #pragma unroll
        for (int t = 0; t < 8; ++t) {
            int c = t * 256 + tid;
            if (c < nchunks) { vtz[c] = (f32x4){0.f,0.f,0.f,0.f}; plz[c] = (f32x4){0.f,0.f,0.f,0.f}; }
        }
    }
    __syncthreads();

    #pragma unroll
    for (int t = 0; t < 7; ++t) {
        int c = t * 256 + tid;
        if (c < NTOK * 8) {
            int row = c >> 3, kc = c & 7;
            bf16x8 kv = *(const bf16x8*)(K + base + (size_t)row * HD + kc * 8);
            *(bf16x8*)&Kl[row][kc * 8] = kv;
            bf16x8 vv = *(const bf16x8*)(V + base + (size_t)row * HD + kc * 8);
            #pragma unroll
            for (int j = 0; j < 8; ++j) VT[kc * 8 + j][row] = (unsigned short)vv[j];
        }
    }
    __syncthreads();

    int qrow_g = qt * 64 + wid * 16 + (lane & 15);
    int qsrc = qrow_g < NTOK ? qrow_g : (NTOK - 1);
    bf16x8 aq[2];
    #pragma unroll
    for (int ks = 0; ks < 2; ++ks)
        aq[ks] = *(const bf16x8*)(Q + base + (size_t)qsrc * HD + ks * 32 + (lane >> 4) * 8);

    f32x4 sa[13];
    #pragma unroll
    for (int t = 0; t < 13; ++t) sa[t] = (f32x4){0.f,0.f,0.f,0.f};
    #pragma unroll
    for (int t = 0; t < 13; ++t) {
        #pragma unroll
        for (int ks = 0; ks < 2; ++ks) {
            bf16x8 bk = *(bf16x8*)&Kl[t * 16 + (lane & 15)][ks * 32 + (lane >> 4) * 8];
            sa[t] = MFMA(aq[ks], bk, sa[t]);
        }
    }

    int rbase = qt * 64 + wid * 16 + (lane >> 4) * 4;
    #pragma unroll
    for (int r = 0; r < 4; ++r) {
        int row_g = rbase + r;
        int rowc = row_g < NTOK ? row_g : (NTOK - 1);
        #pragma unroll
        for (int t = 0; t < 13; ++t) {
            int col = t * 16 + (lane & 15);
            if (col < NTOK) sa[t][r] += biasm[h * NPAIR + rowc * NTOK + col];
            else            sa[t][r] = -1e30f;
        }
        float mx = sa[0][r];
        #pragma unroll
        for (int t = 1; t < 13; ++t) mx = fmaxf(mx, sa[t][r]);
        #pragma unroll
        for (int m = 1; m < 16; m <<= 1) mx = fmaxf(mx, __shfl_xor(mx, m));
        float sum = 0.f;
        #pragma unroll
        for (int t = 0; t < 13; ++t) {
            float e = __expf(sa[t][r] - mx);
            sa[t][r] = e; sum += e;
        }
        #pragma unroll
        for (int m = 1; m < 16; m <<= 1) sum += __shfl_xor(sum, m);
        float inv = 1.f / sum;
        #pragma unroll
        for (int t = 0; t < 13; ++t)
            Pl[wid][(lane >> 4) * 4 + r][t * 16 + (lane & 15)] = f2bf(sa[t][r] * inv);
    }

    f32x4 oa[4];
    #pragma unroll
    for (int dt = 0; dt < 4; ++dt) oa[dt] = (f32x4){0.f,0.f,0.f,0.f};
    #pragma unroll
    for (int ks = 0; ks < 7; ++ks) {
        bf16x8 ap = *(bf16x8*)&Pl[wid][lane & 15][ks * 32 + (lane >> 4) * 8];
        #pragma unroll
        for (int dt = 0; dt < 4; ++dt) {
            bf16x8 bv = *(bf16x8*)&VT[dt * 16 + (lane & 15)][ks * 32 + (lane >> 4) * 8];
            oa[dt] = MFMA(ap, bv, oa[dt]);
        }
    }
    #pragma unroll
    for (int dt = 0; dt < 4; ++dt) {
        #pragma unroll
        for (int r = 0; r < 4; ++r) {
            int row_g = rbase + r;
            if (row_g < NTOK) {
                int col = dt * 16 + (lane & 15);
                O[base + (size_t)row_g * HD + col] = f2bf(oa[dt][r]);
            }
        }
    }
}

// ---------------- GEMM2: out = O @ Wp^T + proj_b (fp32 out), same core as gemm_qkv
__global__ __launch_bounds__(256) void gemm_proj(
    const unsigned short* __restrict__ Ob, const unsigned short* __restrict__ Wp,
    const float* __restrict__ pbias, float* __restrict__ out)
{
    __shared__ __attribute__((aligned(16))) unsigned short As[128 * 64];
    __shared__ __attribute__((aligned(16))) unsigned short Bs[128 * 64];
    int tid = threadIdx.x, lane = tid & 63, wid = tid >> 6;
    int m0 = blockIdx.x * 128, n0 = blockIdx.y * 128;
    int wm = (wid >> 1) * 64, wn = (wid & 1) * 64;

    // A source = Ob [B,H,N,64]; per-lane gather base. Since BK=64 aligns with
    // head dim, addr = base_bn + d(=slot*8) + k0*197.
    size_t abase[4], bbase[4];
    unsigned short *alds[4], *blds[4];
    #pragma unroll
    for (int i = 0; i < 4; ++i) {
        int chunk = i * 4 + wid;
        int row = chunk * 8 + (lane >> 3);
        int slot = (lane & 7) ^ (row & 7);
        int ar = m0 + row; if (ar >= NTOKENS) ar = NTOKENS - 1;
        int b = ar / NTOK, n = ar - b * NTOK;
        abase[i] = ((size_t)(b * NHEADS) * NTOK + n) * HD + slot * 8;
        bbase[i] = (size_t)(n0 + row) * DIM + slot * 8;
        alds[i] = &As[chunk * 512];
        blds[i] = &Bs[chunk * 512];
    }
    int r15 = lane & 15, hi = lane >> 4, sx = lane & 7;
    int s0 = (hi ^ sx) * 8, s1 = ((hi + 4) ^ sx) * 8;
    int arow[4], brow[4];
    #pragma unroll
    for (int i = 0; i < 4; ++i) {
        arow[i] = (wm + i * 16 + r15) * 64;
        brow[i] = (wn + i * 16 + r15) * 64;
    }

    f32x4 acc[4][4];
    #pragma unroll
    for (int i = 0; i < 4; ++i)
        #pragma unroll
        for (int j = 0; j < 4; ++j) acc[i][j] = (f32x4){0.f, 0.f, 0.f, 0.f};

    for (int k0 = 0; k0 < DIM; k0 += 64) {
        __syncthreads();
        #pragma unroll
        for (int i = 0; i < 4; ++i) {
            gload16(Ob + abase[i] + (size_t)k0 * NTOK, alds[i]);   // k0*197 == h*12608
            gload16(Wp + bbase[i] + k0, blds[i]);
        }
        __syncthreads();
        #pragma unroll
        for (int ks = 0; ks < 2; ++ks) {
            int so = ks ? s1 : s0;
            bf16x8 af[4], bw[4];
            #pragma unroll
            for (int i = 0; i < 4; ++i) af[i] = *(bf16x8*)&As[arow[i] + so];
            #pragma unroll
            for (int j = 0; j < 4; ++j) bw[j] = *(bf16x8*)&Bs[brow[j] + so];
            #pragma unroll
            for (int i = 0; i < 4; ++i)
                #pragma unroll
                for (int j = 0; j < 4; ++j)
                    acc[i][j] = MFMA(af[i], bw[j], acc[i][j]);
        }
    }

    #pragma unroll
    for (int j = 0; j < 4; ++j) {
        int col = n0 + wn + j * 16 + r15;
        float bv = pbias[col];
        #pragma unroll
        for (int i = 0; i < 4; ++i) {
            #pragma unroll
            for (int r = 0; r < 4; ++r) {
                int row = m0 + wm + i * 16 + hi * 4 + r;
                if (row < NTOKENS)
                    out[(size_t)row * DIM + col] = acc[i][j][r] + bv;
            }
        }
    }
}

extern "C" void kernel_launch(void* const* d_in, const int* in_sizes, int n_in,
                              void* d_out, int out_size, void* d_ws, size_t ws_size,
                              hipStream_t stream) {
    const float* x      = (const float*)d_in[0];
    const float* qkv_w  = (const float*)d_in[1];
    const float* q_bias = (const float*)d_in[2];
    const float* v_bias = (const float*)d_in[3];
    const float* rpb    = (const float*)d_in[4];
    const float* proj_w = (const float*)d_in[5];
    const float* proj_b = (const float*)d_in[6];
    const int*   rel    = (const int*)d_in[7];
    float* out = (float*)d_out;

    const size_t NELEM = (size_t)NTOKENS * DIM;      // 9,682,944
    const size_t WQKV  = (size_t)3 * DIM * DIM;      // 1,769,472
    const size_t WPROJ = (size_t)DIM * DIM;          //   589,824
    unsigned short* Xb  = (unsigned short*)d_ws;     // reused as Ob after gemm_qkv
    unsigned short* Wqb = Xb + NELEM;
    unsigned short* Wpb = Wqb + WQKV;
    unsigned short* Qb  = Wpb + WPROJ;
    unsigned short* Kb  = Qb + NELEM;
    unsigned short* Vb  = Kb + NELEM;
    float* biasm = (float*)(Vb + NELEM);             // 465,708 floats
    unsigned short* Ob = Xb;                          // alias: Xb dead after gemm_qkv

    to_bf16<<<(int)((NELEM / 8 + 255) / 256), 256, 0, stream>>>(x, Xb, (int)(NELEM / 8));
    to_bf16<<<(int)((WQKV / 8 + 255) / 256), 256, 0, stream>>>(qkv_w, Wqb, (int)(WQKV / 8));
    to_bf16<<<(int)((WPROJ / 8 + 255) / 256), 256, 0, stream>>>(proj_w, Wpb, (int)(WPROJ / 8));
    bias_pre<<<(NHEADS * NPAIR + 255) / 256, 256, 0, stream>>>(rpb, rel, biasm);

    dim3 g1((NTOKENS + 127) / 128, 3 * DIM / 128);   // 99 x 18
    gemm_qkv<<<g1, 256, 0, stream>>>(Xb, Wqb, q_bias, v_bias, Qb, Kb, Vb);

    dim3 ga(4, NHEADS, BATCH);                        // 4 q-tiles x 12 x 64
    attn<<<ga, 256, 0, stream>>>(Qb, Kb, Vb, biasm, Ob);

    dim3 g2((NTOKENS + 127) / 128, DIM / 128);        // 99 x 6
    gemm_proj<<<g2, 256, 0, stream>>>(Ob, Wpb, proj_b, out);
}

// Round 3
// 259.359 us; speedup vs baseline: 1.3089x; 1.0662x over previous
//
#include <hip/hip_runtime.h>
#include <hip/hip_bf16.h>

#define DIM 768
#define NHEADS 12
#define HD 64
#define NTOK 197
#define BATCH 64
#define NTOKENS (BATCH*NTOK)          // 12608
#define NPAIR (NTOK*NTOK)             // 38809
#define QK_SCALE 0.125f               // 64^-0.5

typedef short bf16x8 __attribute__((ext_vector_type(8)));
typedef float f32x4 __attribute__((ext_vector_type(4)));

#define MFMA(a,b,c) __builtin_amdgcn_mfma_f32_16x16x32_bf16(a,b,c,0,0,0)

__device__ __forceinline__ unsigned short f2bf(float f) {
    union { float f; unsigned u; } v; v.f = f;
    unsigned r = v.u + 0x7FFFu + ((v.u >> 16) & 1u);
    return (unsigned short)(r >> 16);
}

__device__ __forceinline__ void gload16(const unsigned short* g, unsigned short* l) {
    __builtin_amdgcn_global_load_lds(
        (const __attribute__((address_space(1))) void*)g,
        (__attribute__((address_space(3))) void*)l, 16, 0, 0);
}

// ---------------- fp32 -> bf16 bulk convert (8 elems/thread)
__global__ __launch_bounds__(256) void to_bf16(const float* __restrict__ s,
                                               unsigned short* __restrict__ d, int n8) {
    int t = blockIdx.x * 256 + threadIdx.x;
    if (t >= n8) return;
    float4 a = ((const float4*)s)[t * 2], b = ((const float4*)s)[t * 2 + 1];
    union { unsigned short u[8]; bf16x8 v; } p;
    p.u[0] = f2bf(a.x); p.u[1] = f2bf(a.y); p.u[2] = f2bf(a.z); p.u[3] = f2bf(a.w);
    p.u[4] = f2bf(b.x); p.u[5] = f2bf(b.y); p.u[6] = f2bf(b.z); p.u[7] = f2bf(b.w);
    ((bf16x8*)d)[t] = p.v;
}

// ---------------- bias precompute: biasm[h][i][j] = rpb[rel[i*197+j]*12 + h]
__global__ __launch_bounds__(256) void bias_pre(const float* __restrict__ rpb,
                                                const int* __restrict__ rel,
                                                float* __restrict__ biasm) {
    int t = blockIdx.x * 256 + threadIdx.x;
    if (t >= NHEADS * NPAIR) return;
    int h = t / NPAIR, p = t - h * NPAIR;
    biasm[t] = rpb[rel[p] * NHEADS + h];
}

// ---------------- GEMM1: qkv = Xb @ Wb^T (+bias), scatter to q/k/v [B,H,N,d]
// 256x256 tile, BK=64, 8 waves (2x4), depth-2 counted-vmcnt pipeline (T3+T4+T5),
// XOR-swizzled LDS via inverse-swizzled global_load_lds source (rule 21).
#define NKT 12          // 768/64 K-tiles
#define BUFE 16384      // elems per buffer (2 halves x 128 x 64)

__global__ __launch_bounds__(512, 2) void gemm_qkv8(
    const unsigned short* __restrict__ Xb, const unsigned short* __restrict__ Wb,
    const float* __restrict__ qbias, const float* __restrict__ vbias,
    unsigned short* __restrict__ Qb, unsigned short* __restrict__ Kb,
    unsigned short* __restrict__ Vb)
{
    __shared__ __attribute__((aligned(16))) unsigned short AsF[2 * BUFE];
    __shared__ __attribute__((aligned(16))) unsigned short BsF[2 * BUFE];
    int tid = threadIdx.x, lane = tid & 63, wid = tid >> 6;
    int wr = wid >> 2, wc = wid & 3;                 // 2 x 4 wave grid
    int m0 = blockIdx.x * 256, n0 = blockIdx.y * 256;
    int r15 = lane & 15, hi = lane >> 4, sx = lane & 7;
    int sl0 = hi ^ sx, sl1 = (hi + 4) ^ sx;          // swizzled 16B-slot indices

    // staging: 4 chunks/thread/operand; chunk c covers row c>>3, slot c&7
    size_t asrc[4], bsrc[4];
    int adoff[4];
    #pragma unroll
    for (int i = 0; i < 4; ++i) {
        int c = i * 512 + tid;
        int row = c >> 3, s = c & 7, rr = row & 127, half = row >> 7;
        int slot = s ^ (rr & 7);
        int ar = m0 + row; if (ar >= NTOKENS) ar = NTOKENS - 1;
        asrc[i] = (size_t)ar * DIM + slot * 8;
        bsrc[i] = (size_t)(n0 + row) * DIM + slot * 8;
        adoff[i] = half * 8192 + rr * 64 + s * 8;    // linear LDS dest (wave-contig)
    }
    int abase0 = wr * 8192 + r15 * 64;               // wave's A-half base
    int bbase0 = (wc >> 1) * 8192 + (wc & 1) * 4096 + r15 * 64;

    f32x4 acc[8][4];
    #pragma unroll
    for (int i = 0; i < 8; ++i)
        #pragma unroll
        for (int j = 0; j < 4; ++j) acc[i][j] = (f32x4){0.f, 0.f, 0.f, 0.f};

#define STAGE(buf, kt) do { \
    _Pragma("unroll") \
    for (int i = 0; i < 4; ++i) { \
        gload16(Xb + asrc[i] + (kt) * 64, &AsF[(buf) * BUFE + adoff[i]]); \
        gload16(Wb + bsrc[i] + (kt) * 64, &BsF[(buf) * BUFE + adoff[i]]); \
    } } while (0)

    bf16x8 af[4][2], bw[2][2];
#define PHASE(mh, nh, LA, LB, bo) do { \
    if (LA) { _Pragma("unroll") for (int mi = 0; mi < 4; ++mi) { \
        af[mi][0] = *(const bf16x8*)&AsF[(bo) + abase0 + ((mh)*4+mi)*1024 + sl0*8]; \
        af[mi][1] = *(const bf16x8*)&AsF[(bo) + abase0 + ((mh)*4+mi)*1024 + sl1*8]; } } \
    if (LB) { _Pragma("unroll") for (int ni = 0; ni < 2; ++ni) { \
        bw[ni][0] = *(const bf16x8*)&BsF[(bo) + bbase0 + ((nh)*2+ni)*1024 + sl0*8]; \
        bw[ni][1] = *(const bf16x8*)&BsF[(bo) + bbase0 + ((nh)*2+ni)*1024 + sl1*8]; } } \
    __builtin_amdgcn_s_setprio(1); \
    _Pragma("unroll") for (int mi = 0; mi < 4; ++mi) \
        _Pragma("unroll") for (int ni = 0; ni < 2; ++ni) { \
            acc[(mh)*4+mi][(nh)*2+ni] = MFMA(af[mi][0], bw[ni][0], acc[(mh)*4+mi][(nh)*2+ni]); \
            acc[(mh)*4+mi][(nh)*2+ni] = MFMA(af[mi][1], bw[ni][1], acc[(mh)*4+mi][(nh)*2+ni]); } \
    __builtin_amdgcn_s_setprio(0); \
} while (0)

    // prologue: tiles 0,1 in flight; wait own tile-0 (8 newest may remain)
    STAGE(0, 0);
    STAGE(1, 1);
    asm volatile("s_waitcnt vmcnt(8)" ::: "memory");
    __builtin_amdgcn_s_barrier();

    for (int t = 0; t < NKT; ++t) {
        int bo = (t & 1) * BUFE;
        PHASE(0, 0, 1, 1, bo);
        PHASE(0, 1, 0, 1, bo);
        PHASE(1, 1, 1, 0, bo);
        PHASE(1, 0, 0, 1, bo);
        __builtin_amdgcn_s_barrier();          // all waves done reading buf t&1
        if (t + 2 < NKT) {
            STAGE(t & 1, t + 2);               // refill just-freed buffer
            asm volatile("s_waitcnt vmcnt(8)" ::: "memory");  // tile t+1 ready
        } else {
            asm volatile("s_waitcnt vmcnt(0)" ::: "memory");  // tail drain
        }
        __builtin_amdgcn_s_barrier();          // buf (t+1)&1 complete for all
    }
#undef STAGE
#undef PHASE

    // epilogue: bias + scale + scatter to q/k/v [B,H,N,d]
    #pragma unroll
    for (int n = 0; n < 4; ++n) {
        int col = n0 + wc * 64 + n * 16 + r15;
        int which = col / DIM;                 // uniform within a 16-col fragment
        int rem = col - which * DIM;
        int hh = rem >> 6, dd = rem & 63;
        float bv = (which == 0) ? qbias[rem] : (which == 2 ? vbias[rem] : 0.f);
        float scl = (which == 0) ? QK_SCALE : 1.f;
        unsigned short* dst = (which == 0) ? Qb : (which == 1 ? Kb : Vb);
        #pragma unroll
        for (int m = 0; m < 8; ++m) {
            #pragma unroll
            for (int r = 0; r < 4; ++r) {
                int row = m0 + wr * 128 + m * 16 + hi * 4 + r;
                if (row < NTOKENS) {
                    int b = row / NTOK, nn = row - b * NTOK;
                    float val = (acc[m][n][r] + bv) * scl;
                    dst[((size_t)(b * NHEADS + hh) * NTOK + nn) * HD + dd] = f2bf(val);
                }
            }
        }
    }
}

// ---------------- fused attention: one block per (q-tile, h, b); 4 waves x 16 q-rows
#define KPITCH 72
#define VPITCH 232

__global__ __launch_bounds__(256) void attn(
    const unsigned short* __restrict__ Q, const unsigned short* __restrict__ K,
    const unsigned short* __restrict__ V, const float* __restrict__ biasm,
    unsigned short* __restrict__ O)
{
    __shared__ __attribute__((aligned(16))) unsigned short Kl[208][KPITCH];
    __shared__ __attribute__((aligned(16))) unsigned short VT[64][VPITCH];
    __shared__ __attribute__((aligned(16))) unsigned short Pl[4][16][VPITCH];

    int tid = threadIdx.x, lane = tid & 63, wid = tid >> 6;
    int qt = blockIdx.x, h = blockIdx.y, b = blockIdx.z;
    size_t base = (size_t)(b * NHEADS + h) * NTOK * HD;

    {
        f32x4* vtz = (f32x4*)&VT[0][0];
        f32x4* plz = (f32x4*)&Pl[0][0][0];
        const int nchunks = 64 * VPITCH * 2 / 16;
        #pragma unroll
        for (int t = 0; t < 8; ++t) {
            int c = t * 256 + tid;
            if (c < nchunks) { vtz[c] = (f32x4){0.f,0.f,0.f,0.f}; plz[c] = (f32x4){0.f,0.f,0.f,0.f}; }
        }
    }
    __syncthreads();

    #pragma unroll
    for (int t = 0; t < 7; ++t) {
        int c = t * 256 + tid;
        if (c < NTOK * 8) {
            int row = c >> 3, kc = c & 7;
            bf16x8 kv = *(const bf16x8*)(K + base + (size_t)row * HD + kc * 8);
            *(bf16x8*)&Kl[row][kc * 8] = kv;
            bf16x8 vv = *(const bf16x8*)(V + base + (size_t)row * HD + kc * 8);
            #pragma unroll
            for (int j = 0; j < 8; ++j) VT[kc * 8 + j][row] = (unsigned short)vv[j];
        }
    }
    __syncthreads();

    int qrow_g = qt * 64 + wid * 16 + (lane & 15);
    int qsrc = qrow_g < NTOK ? qrow_g : (NTOK - 1);
    bf16x8 aq[2];
    #pragma unroll
    for (int ks = 0; ks < 2; ++ks)
        aq[ks] = *(const bf16x8*)(Q + base + (size_t)qsrc * HD + ks * 32 + (lane >> 4) * 8);

    f32x4 sa[13];
    #pragma unroll
    for (int t = 0; t < 13; ++t) sa[t] = (f32x4){0.f,0.f,0.f,0.f};
    #pragma unroll
    for (int t = 0; t < 13; ++t) {
        #pragma unroll
        for (int ks = 0; ks < 2; ++ks) {
            bf16x8 bk = *(bf16x8*)&Kl[t * 16 + (lane & 15)][ks * 32 + (lane >> 4) * 8];
            sa[t] = MFMA(aq[ks], bk, sa[t]);
        }
    }

    int rbase = qt * 64 + wid * 16 + (lane >> 4) * 4;
    #pragma unroll
    for (int r = 0; r < 4; ++r) {
        int row_g = rbase + r;
        int rowc = row_g < NTOK ? row_g : (NTOK - 1);
        #pragma unroll
        for (int t = 0; t < 13; ++t) {
            int col = t * 16 + (lane & 15);
            if (col < NTOK) sa[t][r] += biasm[h * NPAIR + rowc * NTOK + col];
            else            sa[t][r] = -1e30f;
        }
        float mx = sa[0][r];
        #pragma unroll
        for (int t = 1; t < 13; ++t) mx = fmaxf(mx, sa[t][r]);
        #pragma unroll
        for (int m = 1; m < 16; m <<= 1) mx = fmaxf(mx, __shfl_xor(mx, m));
        float sum = 0.f;
        #pragma unroll
        for (int t = 0; t < 13; ++t) {
            float e = __expf(sa[t][r] - mx);
            sa[t][r] = e; sum += e;
        }
        #pragma unroll
        for (int m = 1; m < 16; m <<= 1) sum += __shfl_xor(sum, m);
        float inv = 1.f / sum;
        #pragma unroll
        for (int t = 0; t < 13; ++t)
            Pl[wid][(lane >> 4) * 4 + r][t * 16 + (lane & 15)] = f2bf(sa[t][r] * inv);
    }

    f32x4 oa[4];
    #pragma unroll
    for (int dt = 0; dt < 4; ++dt) oa[dt] = (f32x4){0.f,0.f,0.f,0.f};
    #pragma unroll
    for (int ks = 0; ks < 7; ++ks) {
        bf16x8 ap = *(bf16x8*)&Pl[wid][lane & 15][ks * 32 + (lane >> 4) * 8];
        #pragma unroll
        for (int dt = 0; dt < 4; ++dt) {
            bf16x8 bv = *(bf16x8*)&VT[dt * 16 + (lane & 15)][ks * 32 + (lane >> 4) * 8];
            oa[dt] = MFMA(ap, bv, oa[dt]);
        }
    }
    #pragma unroll
    for (int dt = 0; dt < 4; ++dt) {
        #pragma unroll
        for (int r = 0; r < 4; ++r) {
            int row_g = rbase + r;
            if (row_g < NTOK) {
                int col = dt * 16 + (lane & 15);
                O[base + (size_t)row_g * HD + col] = f2bf(oa[dt][r]);
            }
        }
    }
}

// ---------------- GEMM2: out = O @ Wp^T + proj_b (fp32 out)
__global__ __launch_bounds__(256) void gemm_proj(
    const unsigned short* __restrict__ Ob, const unsigned short* __restrict__ Wp,
    const float* __restrict__ pbias, float* __restrict__ out)
{
    __shared__ __attribute__((aligned(16))) unsigned short As[128 * 64];
    __shared__ __attribute__((aligned(16))) unsigned short Bs[128 * 64];
    int tid = threadIdx.x, lane = tid & 63, wid = tid >> 6;
    int m0 = blockIdx.x * 128, n0 = blockIdx.y * 128;
    int wm = (wid >> 1) * 64, wn = (wid & 1) * 64;

    size_t abase[4], bbase[4];
    unsigned short *alds[4], *blds[4];
    #pragma unroll
    for (int i = 0; i < 4; ++i) {
        int chunk = i * 4 + wid;
        int row = chunk * 8 + (lane >> 3);
        int slot = (lane & 7) ^ (row & 7);
        int ar = m0 + row; if (ar >= NTOKENS) ar = NTOKENS - 1;
        int b = ar / NTOK, n = ar - b * NTOK;
        abase[i] = ((size_t)(b * NHEADS) * NTOK + n) * HD + slot * 8;
        bbase[i] = (size_t)(n0 + row) * DIM + slot * 8;
        alds[i] = &As[chunk * 512];
        blds[i] = &Bs[chunk * 512];
    }
    int r15 = lane & 15, hi = lane >> 4, sx = lane & 7;
    int s0 = (hi ^ sx) * 8, s1 = ((hi + 4) ^ sx) * 8;
    int arow[4], brow[4];
    #pragma unroll
    for (int i = 0; i < 4; ++i) {
        arow[i] = (wm + i * 16 + r15) * 64;
        brow[i] = (wn + i * 16 + r15) * 64;
    }

    f32x4 acc[4][4];
    #pragma unroll
    for (int i = 0; i < 4; ++i)
        #pragma unroll
        for (int j = 0; j < 4; ++j) acc[i][j] = (f32x4){0.f, 0.f, 0.f, 0.f};

    for (int k0 = 0; k0 < DIM; k0 += 64) {
        __syncthreads();
        #pragma unroll
        for (int i = 0; i < 4; ++i) {
            gload16(Ob + abase[i] + (size_t)k0 * NTOK, alds[i]);
            gload16(Wp + bbase[i] + k0, blds[i]);
        }
        __syncthreads();
        #pragma unroll
        for (int ks = 0; ks < 2; ++ks) {
            int so = ks ? s1 : s0;
            bf16x8 af[4], bw[4];
            #pragma unroll
            for (int i = 0; i < 4; ++i) af[i] = *(bf16x8*)&As[arow[i] + so];
            #pragma unroll
            for (int j = 0; j < 4; ++j) bw[j] = *(bf16x8*)&Bs[brow[j] + so];
            #pragma unroll
            for (int i = 0; i < 4; ++i)
                #pragma unroll
                for (int j = 0; j < 4; ++j)
                    acc[i][j] = MFMA(af[i], bw[j], acc[i][j]);
        }
    }

    #pragma unroll
    for (int j = 0; j < 4; ++j) {
        int col = n0 + wn + j * 16 + r15;
        float bv = pbias[col];
        #pragma unroll
        for (int i = 0; i < 4; ++i) {
            #pragma unroll
            for (int r = 0; r < 4; ++r) {
                int row = m0 + wm + i * 16 + hi * 4 + r;
                if (row < NTOKENS)
                    out[(size_t)row * DIM + col] = acc[i][j][r] + bv;
            }
        }
    }
}

extern "C" void kernel_launch(void* const* d_in, const int* in_sizes, int n_in,
                              void* d_out, int out_size, void* d_ws, size_t ws_size,
                              hipStream_t stream) {
    const float* x      = (const float*)d_in[0];
    const float* qkv_w  = (const float*)d_in[1];
    const float* q_bias = (const float*)d_in[2];
    const float* v_bias = (const float*)d_in[3];
    const float* rpb    = (const float*)d_in[4];
    const float* proj_w = (const float*)d_in[5];
    const float* proj_b = (const float*)d_in[6];
    const int*   rel    = (const int*)d_in[7];
    float* out = (float*)d_out;

    const size_t NELEM = (size_t)NTOKENS * DIM;      // 9,682,944
    const size_t WQKV  = (size_t)3 * DIM * DIM;
    const size_t WPROJ = (size_t)DIM * DIM;
    unsigned short* Xb  = (unsigned short*)d_ws;     // reused as Ob after attn
    unsigned short* Wqb = Xb + NELEM;
    unsigned short* Wpb = Wqb + WQKV;
    unsigned short* Qb  = Wpb + WPROJ;
    unsigned short* Kb  = Qb + NELEM;
    unsigned short* Vb  = Kb + NELEM;
    float* biasm = (float*)(Vb + NELEM);
    unsigned short* Ob = Xb;

    to_bf16<<<(int)((NELEM / 8 + 255) / 256), 256, 0, stream>>>(x, Xb, (int)(NELEM / 8));
    to_bf16<<<(int)((WQKV / 8 + 255) / 256), 256, 0, stream>>>(qkv_w, Wqb, (int)(WQKV / 8));
    to_bf16<<<(int)((WPROJ / 8 + 255) / 256), 256, 0, stream>>>(proj_w, Wpb, (int)(WPROJ / 8));
    bias_pre<<<(NHEADS * NPAIR + 255) / 256, 256, 0, stream>>>(rpb, rel, biasm);

    dim3 g1((NTOKENS + 255) / 256, 3 * DIM / 256);   // 50 x 9
    gemm_qkv8<<<g1, 512, 0, stream>>>(Xb, Wqb, q_bias, v_bias, Qb, Kb, Vb);

    dim3 ga(4, NHEADS, BATCH);                        // 4 q-tiles x 12 x 64
    attn<<<ga, 256, 0, stream>>>(Qb, Kb, Vb, biasm, Ob);

    dim3 g2((NTOKENS + 127) / 128, DIM / 128);        // 99 x 6
    gemm_proj<<<g2, 256, 0, stream>>>(Ob, Wpb, proj_b, out);
}

// Round 4
// 227.172 us; speedup vs baseline: 1.4944x; 1.1417x over previous
//
#include <hip/hip_runtime.h>
#include <hip/hip_bf16.h>

#define DIM 768
#define NHEADS 12
#define HD 64
#define NTOK 197
#define BATCH 64
#define NTOKENS (BATCH*NTOK)          // 12608
#define NPAIR (NTOK*NTOK)             // 38809
#define QK_SCALE 0.125f               // 64^-0.5

typedef short bf16x8 __attribute__((ext_vector_type(8)));
typedef float f32x4 __attribute__((ext_vector_type(4)));

#define MFMA(a,b,c) __builtin_amdgcn_mfma_f32_16x16x32_bf16(a,b,c,0,0,0)

__device__ __forceinline__ unsigned short f2bf(float f) {
    union { float f; unsigned u; } v; v.f = f;
    unsigned r = v.u + 0x7FFFu + ((v.u >> 16) & 1u);
    return (unsigned short)(r >> 16);
}

__device__ __forceinline__ void gload16(const unsigned short* g, unsigned short* l) {
    __builtin_amdgcn_global_load_lds(
        (const __attribute__((address_space(1))) void*)g,
        (__attribute__((address_space(3))) void*)l, 16, 0, 0);
}

// ---------------- fp32 -> bf16 bulk convert (8 elems/thread)
__global__ __launch_bounds__(256) void to_bf16(const float* __restrict__ s,
                                               unsigned short* __restrict__ d, int n8) {
    int t = blockIdx.x * 256 + threadIdx.x;
    if (t >= n8) return;
    float4 a = ((const float4*)s)[t * 2], b = ((const float4*)s)[t * 2 + 1];
    union { unsigned short u[8]; bf16x8 v; } p;
    p.u[0] = f2bf(a.x); p.u[1] = f2bf(a.y); p.u[2] = f2bf(a.z); p.u[3] = f2bf(a.w);
    p.u[4] = f2bf(b.x); p.u[5] = f2bf(b.y); p.u[6] = f2bf(b.z); p.u[7] = f2bf(b.w);
    ((bf16x8*)d)[t] = p.v;
}

// ---------------- bias precompute: biasm[h][i][j] = rpb[rel[i*197+j]*12 + h]
__global__ __launch_bounds__(256) void bias_pre(const float* __restrict__ rpb,
                                                const int* __restrict__ rel,
                                                float* __restrict__ biasm) {
    int t = blockIdx.x * 256 + threadIdx.x;
    if (t >= NHEADS * NPAIR) return;
    int h = t / NPAIR, p = t - h * NPAIR;
    biasm[t] = rpb[rel[p] * NHEADS + h];
}

// ---------------- GEMM1: qkv = Xb @ Wb^T (+bias), scatter to q/k/v [B,H,N,d]
#define NKT 12
#define BUFE 16384

__global__ __launch_bounds__(512, 2) void gemm_qkv8(
    const unsigned short* __restrict__ Xb, const unsigned short* __restrict__ Wb,
    const float* __restrict__ qbias, const float* __restrict__ vbias,
    unsigned short* __restrict__ Qb, unsigned short* __restrict__ Kb,
    unsigned short* __restrict__ Vb)
{
    __shared__ __attribute__((aligned(16))) unsigned short AsF[2 * BUFE];
    __shared__ __attribute__((aligned(16))) unsigned short BsF[2 * BUFE];
    int tid = threadIdx.x, lane = tid & 63, wid = tid >> 6;
    int wr = wid >> 2, wc = wid & 3;
    int m0 = blockIdx.x * 256, n0 = blockIdx.y * 256;
    int r15 = lane & 15, hi = lane >> 4, sx = lane & 7;
    int sl0 = hi ^ sx, sl1 = (hi + 4) ^ sx;

    size_t asrc[4], bsrc[4];
    int adoff[4];
    #pragma unroll
    for (int i = 0; i < 4; ++i) {
        int c = i * 512 + tid;
        int row = c >> 3, s = c & 7, rr = row & 127, half = row >> 7;
        int slot = s ^ (rr & 7);
        int ar = m0 + row; if (ar >= NTOKENS) ar = NTOKENS - 1;
        asrc[i] = (size_t)ar * DIM + slot * 8;
        bsrc[i] = (size_t)(n0 + row) * DIM + slot * 8;
        adoff[i] = half * 8192 + rr * 64 + s * 8;
    }
    int abase0 = wr * 8192 + r15 * 64;
    int bbase0 = (wc >> 1) * 8192 + (wc & 1) * 4096 + r15 * 64;

    f32x4 acc[8][4];
    #pragma unroll
    for (int i = 0; i < 8; ++i)
        #pragma unroll
        for (int j = 0; j < 4; ++j) acc[i][j] = (f32x4){0.f, 0.f, 0.f, 0.f};

#define STAGE(buf, kt) do { \
    _Pragma("unroll") \
    for (int i = 0; i < 4; ++i) { \
        gload16(Xb + asrc[i] + (kt) * 64, &AsF[(buf) * BUFE + adoff[i]]); \
        gload16(Wb + bsrc[i] + (kt) * 64, &BsF[(buf) * BUFE + adoff[i]]); \
    } } while (0)

    bf16x8 af[4][2], bw[2][2];
#define PHASE(mh, nh, LA, LB, bo) do { \
    if (LA) { _Pragma("unroll") for (int mi = 0; mi < 4; ++mi) { \
        af[mi][0] = *(const bf16x8*)&AsF[(bo) + abase0 + ((mh)*4+mi)*1024 + sl0*8]; \
        af[mi][1] = *(const bf16x8*)&AsF[(bo) + abase0 + ((mh)*4+mi)*1024 + sl1*8]; } } \
    if (LB) { _Pragma("unroll") for (int ni = 0; ni < 2; ++ni) { \
        bw[ni][0] = *(const bf16x8*)&BsF[(bo) + bbase0 + ((nh)*2+ni)*1024 + sl0*8]; \
        bw[ni][1] = *(const bf16x8*)&BsF[(bo) + bbase0 + ((nh)*2+ni)*1024 + sl1*8]; } } \
    __builtin_amdgcn_s_setprio(1); \
    _Pragma("unroll") for (int mi = 0; mi < 4; ++mi) \
        _Pragma("unroll") for (int ni = 0; ni < 2; ++ni) { \
            acc[(mh)*4+mi][(nh)*2+ni] = MFMA(af[mi][0], bw[ni][0], acc[(mh)*4+mi][(nh)*2+ni]); \
            acc[(mh)*4+mi][(nh)*2+ni] = MFMA(af[mi][1], bw[ni][1], acc[(mh)*4+mi][(nh)*2+ni]); } \
    __builtin_amdgcn_s_setprio(0); \
} while (0)

    STAGE(0, 0);
    STAGE(1, 1);
    asm volatile("s_waitcnt vmcnt(8)" ::: "memory");
    __builtin_amdgcn_s_barrier();

    for (int t = 0; t < NKT; ++t) {
        int bo = (t & 1) * BUFE;
        PHASE(0, 0, 1, 1, bo);
        PHASE(0, 1, 0, 1, bo);
        PHASE(1, 1, 1, 0, bo);
        PHASE(1, 0, 0, 1, bo);
        __builtin_amdgcn_s_barrier();
        if (t + 2 < NKT) {
            STAGE(t & 1, t + 2);
            asm volatile("s_waitcnt vmcnt(8)" ::: "memory");
        } else {
            asm volatile("s_waitcnt vmcnt(0)" ::: "memory");
        }
        __builtin_amdgcn_s_barrier();
    }
#undef STAGE
#undef PHASE

    #pragma unroll
    for (int n = 0; n < 4; ++n) {
        int col = n0 + wc * 64 + n * 16 + r15;
        int which = col / DIM;
        int rem = col - which * DIM;
        int hh = rem >> 6, dd = rem & 63;
        float bv = (which == 0) ? qbias[rem] : (which == 2 ? vbias[rem] : 0.f);
        float scl = (which == 0) ? QK_SCALE : 1.f;
        unsigned short* dst = (which == 0) ? Qb : (which == 1 ? Kb : Vb);
        #pragma unroll
        for (int m = 0; m < 8; ++m) {
            #pragma unroll
            for (int r = 0; r < 4; ++r) {
                int row = m0 + wr * 128 + m * 16 + hi * 4 + r;
                if (row < NTOKENS) {
                    int b = row / NTOK, nn = row - b * NTOK;
                    float val = (acc[m][n][r] + bv) * scl;
                    dst[((size_t)(b * NHEADS + hh) * NTOK + nn) * HD + dd] = f2bf(val);
                }
            }
        }
    }
}

// ---------------- fused attention v2: 57.5 KB LDS (2 blocks/CU), conflict-free
// V^T as packed k-pair u32 [64 d][113 pitch], P aliased onto dead K region.
#define KP 72          // Kl pitch (elems)
#define PP 232         // Pl pitch (elems); 116 dw == 20 mod 32 -> 2-way reads
#define VP32 113       // VT32 pitch (dwords); odd -> d-stride 17 mod 32, CF reads

__global__ __launch_bounds__(256) void attn(
    const unsigned short* __restrict__ Q, const unsigned short* __restrict__ K,
    const unsigned short* __restrict__ V, const float* __restrict__ biasm,
    unsigned short* __restrict__ O)
{
    __shared__ __attribute__((aligned(16))) unsigned int VT32[64 * VP32];     // 28928 B
    __shared__ __attribute__((aligned(16))) unsigned short KlPl[208 * KP];    // 29952 B

    int tid = threadIdx.x, lane = tid & 63, wid = tid >> 6;
    int r15 = lane & 15, hi = lane >> 4;
    int qt = blockIdx.x, h = blockIdx.y, b = blockIdx.z;
    size_t base = (size_t)(b * NHEADS + h) * NTOK * HD;

    // T14: issue all V loads into registers up front (HBM latency hides under
    // K staging + QK^T). Pads load as zero.
    bf16x8 v0r[4], v1r[4];
    #pragma unroll
    for (int it = 0; it < 4; ++it) {
        int c = it * 256 + tid;
        int rp = c >> 3, kc = c & 7;
        int r0 = 2 * rp, r1 = 2 * rp + 1;
        bf16x8 z = (bf16x8)(short)0;
        v0r[it] = z; v1r[it] = z;
        if (r0 < NTOK) v0r[it] = *(const bf16x8*)(V + base + (size_t)r0 * HD + kc * 8);
        if (r1 < NTOK) v1r[it] = *(const bf16x8*)(V + base + (size_t)r1 * HD + kc * 8);
    }

    // stage K rows (row-major, pitch 72 -> 2-way reads)
    #pragma unroll
    for (int t = 0; t < 7; ++t) {
        int c = t * 256 + tid;
        if (c < NTOK * 8) {
            int row = c >> 3, kc = c & 7;
            *(bf16x8*)&KlPl[row * KP + kc * 8] =
                *(const bf16x8*)(K + base + (size_t)row * HD + kc * 8);
        }
    }
    __syncthreads();

    // Q fragments
    int qrow_g = qt * 64 + wid * 16 + r15;
    int qsrc = qrow_g < NTOK ? qrow_g : (NTOK - 1);
    bf16x8 aq[2];
    #pragma unroll
    for (int ks = 0; ks < 2; ++ks)
        aq[ks] = *(const bf16x8*)(Q + base + (size_t)qsrc * HD + ks * 32 + hi * 8);

    // S = Q K^T (rows >=197 of Kl are garbage; masked before exp)
    f32x4 sa[13];
    #pragma unroll
    for (int t = 0; t < 13; ++t) sa[t] = (f32x4){0.f,0.f,0.f,0.f};
    __builtin_amdgcn_s_setprio(1);
    #pragma unroll
    for (int t = 0; t < 13; ++t) {
        #pragma unroll
        for (int ks = 0; ks < 2; ++ks) {
            bf16x8 bk = *(bf16x8*)&KlPl[(t * 16 + r15) * KP + ks * 32 + hi * 8];
            sa[t] = MFMA(aq[ks], bk, sa[t]);
        }
    }
    __builtin_amdgcn_s_setprio(0);
    __syncthreads();          // all waves past QK^T: Kl region becomes Pl

    // write V regs -> VT32 (overlaps softmax VALU below across waves)
    #pragma unroll
    for (int it = 0; it < 4; ++it) {
        int c = it * 256 + tid;
        int rp = c >> 3, kc = c & 7;
        if (rp < 112) {
            #pragma unroll
            for (int j = 0; j < 8; ++j) {
                unsigned int w = (unsigned int)(unsigned short)v0r[it][j] |
                                 ((unsigned int)(unsigned short)v1r[it][j] << 16);
                VT32[(kc * 8 + j) * VP32 + rp] = w;
            }
        }
    }

    // softmax -> P (bf16) into KlPl region
    int plbase = wid * (16 * PP);
    int rbase = qt * 64 + wid * 16 + hi * 4;
    #pragma unroll
    for (int r = 0; r < 4; ++r) {
        int row_g = rbase + r;
        int rowc = row_g < NTOK ? row_g : (NTOK - 1);
        #pragma unroll
        for (int t = 0; t < 13; ++t) {
            int col = t * 16 + r15;
            if (col < NTOK) sa[t][r] += biasm[h * NPAIR + rowc * NTOK + col];
            else            sa[t][r] = -1e30f;
        }
        float mx = sa[0][r];
        #pragma unroll
        for (int t = 1; t < 13; ++t) mx = fmaxf(mx, sa[t][r]);
        #pragma unroll
        for (int m = 1; m < 16; m <<= 1) mx = fmaxf(mx, __shfl_xor(mx, m));
        float sum = 0.f;
        #pragma unroll
        for (int t = 0; t < 13; ++t) {
            float e = __expf(sa[t][r] - mx);
            sa[t][r] = e; sum += e;
        }
        #pragma unroll
        for (int m = 1; m < 16; m <<= 1) sum += __shfl_xor(sum, m);
        float inv = 1.f / sum;
        int roff = plbase + (hi * 4 + r) * PP;
        #pragma unroll
        for (int t = 0; t < 13; ++t)
            KlPl[roff + t * 16 + r15] = f2bf(sa[t][r] * inv);
        KlPl[roff + 208 + r15] = 0;        // zero pad cols 208..223 (PV reads them)
    }
    __syncthreads();          // VT32 fully written

    // O = P V
    f32x4 oa[4];
    #pragma unroll
    for (int dt = 0; dt < 4; ++dt) oa[dt] = (f32x4){0.f,0.f,0.f,0.f};
    __builtin_amdgcn_s_setprio(1);
    #pragma unroll
    for (int ks = 0; ks < 7; ++ks) {
        bf16x8 ap = *(bf16x8*)&KlPl[plbase + r15 * PP + ks * 32 + hi * 8];
        #pragma unroll
        for (int dt = 0; dt < 4; ++dt) {
            union { unsigned int u[4]; bf16x8 v; } bv;
            int d = dt * 16 + r15;
            int rp = ks * 16 + hi * 4;
            bv.u[0] = VT32[d * VP32 + rp];
            bv.u[1] = VT32[d * VP32 + rp + 1];
            bv.u[2] = VT32[d * VP32 + rp + 2];
            bv.u[3] = VT32[d * VP32 + rp + 3];
            oa[dt] = MFMA(ap, bv.v, oa[dt]);
        }
    }
    __builtin_amdgcn_s_setprio(0);
    #pragma unroll
    for (int dt = 0; dt < 4; ++dt) {
        #pragma unroll
        for (int r = 0; r < 4; ++r) {
            int row_g = rbase + r;
            if (row_g < NTOK) {
                int col = dt * 16 + r15;
                O[base + (size_t)row_g * HD + col] = f2bf(oa[dt][r]);
            }
        }
    }
}

// ---------------- GEMM2: out = O @ Wp^T + proj_b (fp32 out)
__global__ __launch_bounds__(256) void gemm_proj(
    const unsigned short* __restrict__ Ob, const unsigned short* __restrict__ Wp,
    const float* __restrict__ pbias, float* __restrict__ out)
{
    __shared__ __attribute__((aligned(16))) unsigned short As[128 * 64];
    __shared__ __attribute__((aligned(16))) unsigned short Bs[128 * 64];
    int tid = threadIdx.x, lane = tid & 63, wid = tid >> 6;
    int m0 = blockIdx.x * 128, n0 = blockIdx.y * 128;
    int wm = (wid >> 1) * 64, wn = (wid & 1) * 64;

    size_t abase[4], bbase[4];
    unsigned short *alds[4], *blds[4];
    #pragma unroll
    for (int i = 0; i < 4; ++i) {
        int chunk = i * 4 + wid;
        int row = chunk * 8 + (lane >> 3);
        int slot = (lane & 7) ^ (row & 7);
        int ar = m0 + row; if (ar >= NTOKENS) ar = NTOKENS - 1;
        int b = ar / NTOK, n = ar - b * NTOK;
        abase[i] = ((size_t)(b * NHEADS) * NTOK + n) * HD + slot * 8;
        bbase[i] = (size_t)(n0 + row) * DIM + slot * 8;
        alds[i] = &As[chunk * 512];
        blds[i] = &Bs[chunk * 512];
    }
    int r15 = lane & 15, hi = lane >> 4, sx = lane & 7;
    int s0 = (hi ^ sx) * 8, s1 = ((hi + 4) ^ sx) * 8;
    int arow[4], brow[4];
    #pragma unroll
    for (int i = 0; i < 4; ++i) {
        arow[i] = (wm + i * 16 + r15) * 64;
        brow[i] = (wn + i * 16 + r15) * 64;
    }

    f32x4 acc[4][4];
    #pragma unroll
    for (int i = 0; i < 4; ++i)
        #pragma unroll
        for (int j = 0; j < 4; ++j) acc[i][j] = (f32x4){0.f, 0.f, 0.f, 0.f};

    for (int k0 = 0; k0 < DIM; k0 += 64) {
        __syncthreads();
        #pragma unroll
        for (int i = 0; i < 4; ++i) {
            gload16(Ob + abase[i] + (size_t)k0 * NTOK, alds[i]);
            gload16(Wp + bbase[i] + k0, blds[i]);
        }
        __syncthreads();
        #pragma unroll
        for (int ks = 0; ks < 2; ++ks) {
            int so = ks ? s1 : s0;
            bf16x8 af[4], bw[4];
            #pragma unroll
            for (int i = 0; i < 4; ++i) af[i] = *(bf16x8*)&As[arow[i] + so];
            #pragma unroll
            for (int j = 0; j < 4; ++j) bw[j] = *(bf16x8*)&Bs[brow[j] + so];
            #pragma unroll
            for (int i = 0; i < 4; ++i)
                #pragma unroll
                for (int j = 0; j < 4; ++j)
                    acc[i][j] = MFMA(af[i], bw[j], acc[i][j]);
        }
    }

    #pragma unroll
    for (int j = 0; j < 4; ++j) {
        int col = n0 + wn + j * 16 + r15;
        float bv = pbias[col];
        #pragma unroll
        for (int i = 0; i < 4; ++i) {
            #pragma unroll
            for (int r = 0; r < 4; ++r) {
                int row = m0 + wm + i * 16 + hi * 4 + r;
                if (row < NTOKENS)
                    out[(size_t)row * DIM + col] = acc[i][j][r] + bv;
            }
        }
    }
}

extern "C" void kernel_launch(void* const* d_in, const int* in_sizes, int n_in,
                              void* d_out, int out_size, void* d_ws, size_t ws_size,
                              hipStream_t stream) {
    const float* x      = (const float*)d_in[0];
    const float* qkv_w  = (const float*)d_in[1];
    const float* q_bias = (const float*)d_in[2];
    const float* v_bias = (const float*)d_in[3];
    const float* rpb    = (const float*)d_in[4];
    const float* proj_w = (const float*)d_in[5];
    const float* proj_b = (const float*)d_in[6];
    const int*   rel    = (const int*)d_in[7];
    float* out = (float*)d_out;

    const size_t NELEM = (size_t)NTOKENS * DIM;
    const size_t WQKV  = (size_t)3 * DIM * DIM;
    const size_t WPROJ = (size_t)DIM * DIM;
    unsigned short* Xb  = (unsigned short*)d_ws;
    unsigned short* Wqb = Xb + NELEM;
    unsigned short* Wpb = Wqb + WQKV;
    unsigned short* Qb  = Wpb + WPROJ;
    unsigned short* Kb  = Qb + NELEM;
    unsigned short* Vb  = Kb + NELEM;
    float* biasm = (float*)(Vb + NELEM);
    unsigned short* Ob = Xb;

    to_bf16<<<(int)((NELEM / 8 + 255) / 256), 256, 0, stream>>>(x, Xb, (int)(NELEM / 8));
    to_bf16<<<(int)((WQKV / 8 + 255) / 256), 256, 0, stream>>>(qkv_w, Wqb, (int)(WQKV / 8));
    to_bf16<<<(int)((WPROJ / 8 + 255) / 256), 256, 0, stream>>>(proj_w, Wpb, (int)(WPROJ / 8));
    bias_pre<<<(NHEADS * NPAIR + 255) / 256, 256, 0, stream>>>(rpb, rel, biasm);

    dim3 g1((NTOKENS + 255) / 256, 3 * DIM / 256);   // 50 x 9
    gemm_qkv8<<<g1, 512, 0, stream>>>(Xb, Wqb, q_bias, v_bias, Qb, Kb, Vb);

    dim3 ga(4, NHEADS, BATCH);
    attn<<<ga, 256, 0, stream>>>(Qb, Kb, Vb, biasm, Ob);

    dim3 g2((NTOKENS + 127) / 128, DIM / 128);        // 99 x 6
    gemm_proj<<<g2, 256, 0, stream>>>(Ob, Wpb, proj_b, out);
}

// Round 5
// 196.920 us; speedup vs baseline: 1.7240x; 1.1536x over previous
//
#include <hip/hip_runtime.h>
#include <hip/hip_bf16.h>

#define DIM 768
#define NHEADS 12
#define HD 64
#define NTOK 197
#define BATCH 64
#define NTOKENS (BATCH*NTOK)          // 12608
#define NPAIR (NTOK*NTOK)             // 38809
#define QK_SCALE 0.125f               // 64^-0.5
#define CDIM 2304                     // qkv row width

typedef short bf16x8 __attribute__((ext_vector_type(8)));
typedef float f32x4 __attribute__((ext_vector_type(4)));

#define MFMA(a,b,c) __builtin_amdgcn_mfma_f32_16x16x32_bf16(a,b,c,0,0,0)

__device__ __forceinline__ unsigned short f2bf(float f) {
    union { float f; unsigned u; } v; v.f = f;
    unsigned r = v.u + 0x7FFFu + ((v.u >> 16) & 1u);
    return (unsigned short)(r >> 16);
}

__device__ __forceinline__ void gload16(const unsigned short* g, unsigned short* l) {
    __builtin_amdgcn_global_load_lds(
        (const __attribute__((address_space(1))) void*)g,
        (__attribute__((address_space(3))) void*)l, 16, 0, 0);
}

// bijective XCD-aware block swizzle (m204)
__device__ __forceinline__ int xcd_swz(int orig, int nwg) {
    int q = nwg >> 3, r = nwg & 7;
    int xcd = orig & 7, idx = orig >> 3;
    return (xcd < r ? xcd * (q + 1) : r * (q + 1) + (xcd - r) * q) + idx;
}

// ---------------- fp32 -> bf16 bulk convert (8 elems/thread)
__global__ __launch_bounds__(256) void to_bf16(const float* __restrict__ s,
                                               unsigned short* __restrict__ d, int n8) {
    int t = blockIdx.x * 256 + threadIdx.x;
    if (t >= n8) return;
    float4 a = ((const float4*)s)[t * 2], b = ((const float4*)s)[t * 2 + 1];
    union { unsigned short u[8]; bf16x8 v; } p;
    p.u[0] = f2bf(a.x); p.u[1] = f2bf(a.y); p.u[2] = f2bf(a.z); p.u[3] = f2bf(a.w);
    p.u[4] = f2bf(b.x); p.u[5] = f2bf(b.y); p.u[6] = f2bf(b.z); p.u[7] = f2bf(b.w);
    ((bf16x8*)d)[t] = p.v;
}

// ---------------- bias precompute: biasm[h][i][j] = rpb[rel[i*197+j]*12 + h]
__global__ __launch_bounds__(256) void bias_pre(const float* __restrict__ rpb,
                                                const int* __restrict__ rel,
                                                float* __restrict__ biasm) {
    int t = blockIdx.x * 256 + threadIdx.x;
    if (t >= NHEADS * NPAIR) return;
    int h = t / NPAIR, p = t - h * NPAIR;
    biasm[t] = rpb[rel[p] * NHEADS + h];
}

// ---------------- GEMM1: qkv[token][2304] = Xb @ Wb^T (+bias, Q pre-scaled)
#define NKT 12
#define BUFE 16384

__global__ __launch_bounds__(512, 2) void gemm_qkv8(
    const unsigned short* __restrict__ Xb, const unsigned short* __restrict__ Wb,
    const float* __restrict__ qbias, const float* __restrict__ vbias,
    unsigned short* __restrict__ QKVb)
{
    __shared__ __attribute__((aligned(16))) unsigned short AsF[2 * BUFE];
    __shared__ __attribute__((aligned(16))) unsigned short BsF[2 * BUFE];
    int tid = threadIdx.x, lane = tid & 63, wid = tid >> 6;
    int wr = wid >> 2, wc = wid & 3;
    int wg = xcd_swz(blockIdx.x, 450);
    int bx = wg % 50, by = wg / 50;           // consecutive wg share W-panel
    int m0 = bx * 256, n0 = by * 256;
    int r15 = lane & 15, hi = lane >> 4, sx = lane & 7;
    int sl0 = hi ^ sx, sl1 = (hi + 4) ^ sx;

    size_t asrc[4], bsrc[4];
    int adoff[4];
    #pragma unroll
    for (int i = 0; i < 4; ++i) {
        int c = i * 512 + tid;
        int row = c >> 3, s = c & 7, rr = row & 127, half = row >> 7;
        int slot = s ^ (rr & 7);
        int ar = m0 + row; if (ar >= NTOKENS) ar = NTOKENS - 1;
        asrc[i] = (size_t)ar * DIM + slot * 8;
        bsrc[i] = (size_t)(n0 + row) * DIM + slot * 8;
        adoff[i] = half * 8192 + rr * 64 + s * 8;
    }
    int abase0 = wr * 8192 + r15 * 64;
    int bbase0 = (wc >> 1) * 8192 + (wc & 1) * 4096 + r15 * 64;

    f32x4 acc[8][4];
    #pragma unroll
    for (int i = 0; i < 8; ++i)
        #pragma unroll
        for (int j = 0; j < 4; ++j) acc[i][j] = (f32x4){0.f, 0.f, 0.f, 0.f};

#define STAGE(buf, kt) do { \
    _Pragma("unroll") \
    for (int i = 0; i < 4; ++i) { \
        gload16(Xb + asrc[i] + (kt) * 64, &AsF[(buf) * BUFE + adoff[i]]); \
        gload16(Wb + bsrc[i] + (kt) * 64, &BsF[(buf) * BUFE + adoff[i]]); \
    } } while (0)

    bf16x8 af[4][2], bw[2][2];
#define PHASE(mh, nh, LA, LB, bo) do { \
    if (LA) { _Pragma("unroll") for (int mi = 0; mi < 4; ++mi) { \
        af[mi][0] = *(const bf16x8*)&AsF[(bo) + abase0 + ((mh)*4+mi)*1024 + sl0*8]; \
        af[mi][1] = *(const bf16x8*)&AsF[(bo) + abase0 + ((mh)*4+mi)*1024 + sl1*8]; } } \
    if (LB) { _Pragma("unroll") for (int ni = 0; ni < 2; ++ni) { \
        bw[ni][0] = *(const bf16x8*)&BsF[(bo) + bbase0 + ((nh)*2+ni)*1024 + sl0*8]; \
        bw[ni][1] = *(const bf16x8*)&BsF[(bo) + bbase0 + ((nh)*2+ni)*1024 + sl1*8]; } } \
    __builtin_amdgcn_s_setprio(1); \
    _Pragma("unroll") for (int mi = 0; mi < 4; ++mi) \
        _Pragma("unroll") for (int ni = 0; ni < 2; ++ni) { \
            acc[(mh)*4+mi][(nh)*2+ni] = MFMA(af[mi][0], bw[ni][0], acc[(mh)*4+mi][(nh)*2+ni]); \
            acc[(mh)*4+mi][(nh)*2+ni] = MFMA(af[mi][1], bw[ni][1], acc[(mh)*4+mi][(nh)*2+ni]); } \
    __builtin_amdgcn_s_setprio(0); \
} while (0)

    STAGE(0, 0);
    STAGE(1, 1);
    asm volatile("s_waitcnt vmcnt(8)" ::: "memory");
    __builtin_amdgcn_s_barrier();

    for (int t = 0; t < NKT; ++t) {
        int bo = (t & 1) * BUFE;
        PHASE(0, 0, 1, 1, bo);
        PHASE(0, 1, 0, 1, bo);
        PHASE(1, 1, 1, 0, bo);
        PHASE(1, 0, 0, 1, bo);
        __builtin_amdgcn_s_barrier();
        if (t + 2 < NKT) {
            STAGE(t & 1, t + 2);
            asm volatile("s_waitcnt vmcnt(8)" ::: "memory");
        } else {
            asm volatile("s_waitcnt vmcnt(0)" ::: "memory");
        }
        __builtin_amdgcn_s_barrier();
    }
#undef STAGE
#undef PHASE

    // epilogue: bias+scale in regs -> per-wave LDS transpose -> coalesced stores.
    // LDS (both buffers) is dead after the final barrier; each wave owns 16 KB.
    unsigned short* reg = (wid < 4) ? &AsF[wid * 8192] : &BsF[(wid - 4) * 8192];
    {
        int which = n0 / DIM;                  // block-uniform (768 = 3*256)
        float scl = (which == 0) ? QK_SCALE : 1.f;
        #pragma unroll
        for (int n = 0; n < 4; ++n) {
            int colr = n0 - which * DIM + wc * 64 + n * 16 + r15;
            float bv = (which == 0) ? qbias[colr] : (which == 2 ? vbias[colr] : 0.f);
            #pragma unroll
            for (int m = 0; m < 8; ++m) {
                int lrb = m * 16 + hi * 4;
                #pragma unroll
                for (int r = 0; r < 4; ++r) {
                    int lr = lrb + r;
                    int c = n * 16 + r15;
                    reg[lr * 64 + (c ^ (((lr >> 2) & 3) << 4))] =
                        f2bf((acc[m][n][r] + bv) * scl);
                }
            }
        }
    }
    // readback own region (in-wave DS ordering) + 16B coalesced stores
    #pragma unroll
    for (int it = 0; it < 16; ++it) {
        int c = it * 64 + lane;
        int lr = c >> 3, cc = c & 7;
        int row = m0 + wr * 128 + lr;
        if (row < NTOKENS) {
            bf16x8 v = *(bf16x8*)&reg[lr * 64 + ((cc * 8) ^ (((lr >> 2) & 3) << 4))];
            *(bf16x8*)(QKVb + (size_t)row * CDIM + n0 + wc * 64 + cc * 8) = v;
        }
    }
}

// ---------------- fused attention: QKV[token][2304] in, O[token][768] out
#define KP 72          // Kl pitch (elems)
#define PP 232         // Pl pitch (elems)
#define VP32 113       // VT32 pitch (dwords); odd -> conflict-free cols

__global__ __launch_bounds__(256) void attn(
    const unsigned short* __restrict__ QKV, const float* __restrict__ biasm,
    unsigned short* __restrict__ O)
{
    __shared__ __attribute__((aligned(16))) unsigned int VT32[64 * VP32];     // 28928 B
    __shared__ __attribute__((aligned(16))) unsigned short KlPl[208 * KP];    // 29952 B

    int tid = threadIdx.x, lane = tid & 63, wid = tid >> 6;
    int r15 = lane & 15, hi = lane >> 4;
    int qt = blockIdx.x, h = blockIdx.y, b = blockIdx.z;
    size_t tb = (size_t)b * NTOK;              // token row base
    int hq = h * 64;

    // T14: V loads into regs up front (latency hides under K staging + QK^T)
    bf16x8 v0r[4], v1r[4];
    #pragma unroll
    for (int it = 0; it < 4; ++it) {
        int c = it * 256 + tid;
        int rp = c >> 3, kc = c & 7;
        int r0 = 2 * rp, r1 = 2 * rp + 1;
        bf16x8 z = (bf16x8)(short)0;
        v0r[it] = z; v1r[it] = z;
        if (r0 < NTOK) v0r[it] = *(const bf16x8*)(QKV + (tb + r0) * CDIM + 1536 + hq + kc * 8);
        if (r1 < NTOK) v1r[it] = *(const bf16x8*)(QKV + (tb + r1) * CDIM + 1536 + hq + kc * 8);
    }

    // stage K rows
    #pragma unroll
    for (int t = 0; t < 7; ++t) {
        int c = t * 256 + tid;
        if (c < NTOK * 8) {
            int row = c >> 3, kc = c & 7;
            *(bf16x8*)&KlPl[row * KP + kc * 8] =
                *(const bf16x8*)(QKV + (tb + row) * CDIM + 768 + hq + kc * 8);
        }
    }
    __syncthreads();

    // Q fragments
    int qrow_g = qt * 64 + wid * 16 + r15;
    int qsrc = qrow_g < NTOK ? qrow_g : (NTOK - 1);
    bf16x8 aq[2];
    #pragma unroll
    for (int ks = 0; ks < 2; ++ks)
        aq[ks] = *(const bf16x8*)(QKV + (tb + qsrc) * CDIM + hq + ks * 32 + hi * 8);

    // S = Q K^T
    f32x4 sa[13];
    #pragma unroll
    for (int t = 0; t < 13; ++t) sa[t] = (f32x4){0.f,0.f,0.f,0.f};
    __builtin_amdgcn_s_setprio(1);
    #pragma unroll
    for (int t = 0; t < 13; ++t) {
        #pragma unroll
        for (int ks = 0; ks < 2; ++ks) {
            bf16x8 bk = *(bf16x8*)&KlPl[(t * 16 + r15) * KP + ks * 32 + hi * 8];
            sa[t] = MFMA(aq[ks], bk, sa[t]);
        }
    }
    __builtin_amdgcn_s_setprio(0);
    __syncthreads();          // all waves past QK^T: Kl region becomes Pl

    // V regs -> VT32 (packed row-pairs)
    #pragma unroll
    for (int it = 0; it < 4; ++it) {
        int c = it * 256 + tid;
        int rp = c >> 3, kc = c & 7;
        if (rp < 112) {
            #pragma unroll
            for (int j = 0; j < 8; ++j) {
                unsigned int w = (unsigned int)(unsigned short)v0r[it][j] |
                                 ((unsigned int)(unsigned short)v1r[it][j] << 16);
                VT32[(kc * 8 + j) * VP32 + rp] = w;
            }
        }
    }

    // softmax -> P (bf16) into KlPl region
    int plbase = wid * (16 * PP);
    int rbase = qt * 64 + wid * 16 + hi * 4;
    #pragma unroll
    for (int r = 0; r < 4; ++r) {
        int row_g = rbase + r;
        int rowc = row_g < NTOK ? row_g : (NTOK - 1);
        #pragma unroll
        for (int t = 0; t < 13; ++t) {
            int col = t * 16 + r15;
            if (col < NTOK) sa[t][r] += biasm[h * NPAIR + rowc * NTOK + col];
            else            sa[t][r] = -1e30f;
        }
        float mx = sa[0][r];
        #pragma unroll
        for (int t = 1; t < 13; ++t) mx = fmaxf(mx, sa[t][r]);
        #pragma unroll
        for (int m = 1; m < 16; m <<= 1) mx = fmaxf(mx, __shfl_xor(mx, m));
        float sum = 0.f;
        #pragma unroll
        for (int t = 0; t < 13; ++t) {
            float e = __expf(sa[t][r] - mx);
            sa[t][r] = e; sum += e;
        }
        #pragma unroll
        for (int m = 1; m < 16; m <<= 1) sum += __shfl_xor(sum, m);
        float inv = 1.f / sum;
        int roff = plbase + (hi * 4 + r) * PP;
        #pragma unroll
        for (int t = 0; t < 13; ++t)
            KlPl[roff + t * 16 + r15] = f2bf(sa[t][r] * inv);
        KlPl[roff + 208 + r15] = 0;
    }
    __syncthreads();          // VT32 fully written

    // O = P V
    f32x4 oa[4];
    #pragma unroll
    for (int dt = 0; dt < 4; ++dt) oa[dt] = (f32x4){0.f,0.f,0.f,0.f};
    __builtin_amdgcn_s_setprio(1);
    #pragma unroll
    for (int ks = 0; ks < 7; ++ks) {
        bf16x8 ap = *(bf16x8*)&KlPl[plbase + r15 * PP + ks * 32 + hi * 8];
        #pragma unroll
        for (int dt = 0; dt < 4; ++dt) {
            union { unsigned int u[4]; bf16x8 v; } bv;
            int d = dt * 16 + r15;
            int rp = ks * 16 + hi * 4;
            bv.u[0] = VT32[d * VP32 + rp];
            bv.u[1] = VT32[d * VP32 + rp + 1];
            bv.u[2] = VT32[d * VP32 + rp + 2];
            bv.u[3] = VT32[d * VP32 + rp + 3];
            oa[dt] = MFMA(ap, bv.v, oa[dt]);
        }
    }
    __builtin_amdgcn_s_setprio(0);

    // O write via per-wave LDS transpose (own Pl region, pitch 72) -> 16B stores
    #pragma unroll
    for (int dt = 0; dt < 4; ++dt)
        #pragma unroll
        for (int r = 0; r < 4; ++r)
            KlPl[plbase + (hi * 4 + r) * 72 + dt * 16 + r15] = f2bf(oa[dt][r]);
    #pragma unroll
    for (int it = 0; it < 2; ++it) {
        int c = it * 64 + lane;
        int lr = c >> 3, cc = c & 7;
        int qrow = qt * 64 + wid * 16 + lr;
        if (qrow < NTOK)
            *(bf16x8*)(O + (tb + qrow) * DIM + hq + cc * 8) =
                *(bf16x8*)&KlPl[plbase + lr * 72 + cc * 8];
    }
}

// ---------------- GEMM2: out = O @ Wp^T + proj_b (fp32 out)
__global__ __launch_bounds__(256) void gemm_proj(
    const unsigned short* __restrict__ Ob, const unsigned short* __restrict__ Wp,
    const float* __restrict__ pbias, float* __restrict__ out)
{
    __shared__ __attribute__((aligned(16))) unsigned short As[128 * 64];
    __shared__ __attribute__((aligned(16))) unsigned short Bs[128 * 64];
    int tid = threadIdx.x, lane = tid & 63, wid = tid >> 6;
    int wg = xcd_swz(blockIdx.x, 594);
    int bx = wg % 99, by = wg / 99;
    int m0 = bx * 128, n0 = by * 128;
    int wm = (wid >> 1) * 64, wn = (wid & 1) * 64;

    size_t abase[4], bbase[4];
    unsigned short *alds[4], *blds[4];
    #pragma unroll
    for (int i = 0; i < 4; ++i) {
        int chunk = i * 4 + wid;
        int row = chunk * 8 + (lane >> 3);
        int slot = (lane & 7) ^ (row & 7);
        int ar = m0 + row; if (ar >= NTOKENS) ar = NTOKENS - 1;
        abase[i] = (size_t)ar * DIM + slot * 8;
        bbase[i] = (size_t)(n0 + row) * DIM + slot * 8;
        alds[i] = &As[chunk * 512];
        blds[i] = &Bs[chunk * 512];
    }
    int r15 = lane & 15, hi = lane >> 4, sx = lane & 7;
    int s0 = (hi ^ sx) * 8, s1 = ((hi + 4) ^ sx) * 8;
    int arow[4], brow[4];
    #pragma unroll
    for (int i = 0; i < 4; ++i) {
        arow[i] = (wm + i * 16 + r15) * 64;
        brow[i] = (wn + i * 16 + r15) * 64;
    }

    f32x4 acc[4][4];
    #pragma unroll
    for (int i = 0; i < 4; ++i)
        #pragma unroll
        for (int j = 0; j < 4; ++j) acc[i][j] = (f32x4){0.f, 0.f, 0.f, 0.f};

    for (int k0 = 0; k0 < DIM; k0 += 64) {
        __syncthreads();
        #pragma unroll
        for (int i = 0; i < 4; ++i) {
            gload16(Ob + abase[i] + k0, alds[i]);
            gload16(Wp + bbase[i] + k0, blds[i]);
        }
        __syncthreads();
        #pragma unroll
        for (int ks = 0; ks < 2; ++ks) {
            int so = ks ? s1 : s0;
            bf16x8 af[4], bw[4];
            #pragma unroll
            for (int i = 0; i < 4; ++i) af[i] = *(bf16x8*)&As[arow[i] + so];
            #pragma unroll
            for (int j = 0; j < 4; ++j) bw[j] = *(bf16x8*)&Bs[brow[j] + so];
            #pragma unroll
            for (int i = 0; i < 4; ++i)
                #pragma unroll
                for (int j = 0; j < 4; ++j)
                    acc[i][j] = MFMA(af[i], bw[j], acc[i][j]);
        }
    }

    #pragma unroll
    for (int j = 0; j < 4; ++j) {
        int col = n0 + wn + j * 16 + r15;
        float bv = pbias[col];
        #pragma unroll
        for (int i = 0; i < 4; ++i) {
            #pragma unroll
            for (int r = 0; r < 4; ++r) {
                int row = m0 + wm + i * 16 + hi * 4 + r;
                if (row < NTOKENS)
                    out[(size_t)row * DIM + col] = acc[i][j][r] + bv;
            }
        }
    }
}

extern "C" void kernel_launch(void* const* d_in, const int* in_sizes, int n_in,
                              void* d_out, int out_size, void* d_ws, size_t ws_size,
                              hipStream_t stream) {
    const float* x      = (const float*)d_in[0];
    const float* qkv_w  = (const float*)d_in[1];
    const float* q_bias = (const float*)d_in[2];
    const float* v_bias = (const float*)d_in[3];
    const float* rpb    = (const float*)d_in[4];
    const float* proj_w = (const float*)d_in[5];
    const float* proj_b = (const float*)d_in[6];
    const int*   rel    = (const int*)d_in[7];
    float* out = (float*)d_out;

    const size_t NELEM = (size_t)NTOKENS * DIM;      // 9,682,944
    const size_t WQKV  = (size_t)3 * DIM * DIM;
    const size_t WPROJ = (size_t)DIM * DIM;
    unsigned short* Xb   = (unsigned short*)d_ws;    // reused as Ob after gemm_qkv8
    unsigned short* Wqb  = Xb + NELEM;
    unsigned short* Wpb  = Wqb + WQKV;
    unsigned short* QKVb = Wpb + WPROJ;              // [12608][2304]
    float* biasm = (float*)(QKVb + (size_t)NTOKENS * CDIM);
    unsigned short* Ob = Xb;

    to_bf16<<<(int)((NELEM / 8 + 255) / 256), 256, 0, stream>>>(x, Xb, (int)(NELEM / 8));
    to_bf16<<<(int)((WQKV / 8 + 255) / 256), 256, 0, stream>>>(qkv_w, Wqb, (int)(WQKV / 8));
    to_bf16<<<(int)((WPROJ / 8 + 255) / 256), 256, 0, stream>>>(proj_w, Wpb, (int)(WPROJ / 8));
    bias_pre<<<(NHEADS * NPAIR + 255) / 256, 256, 0, stream>>>(rpb, rel, biasm);

    gemm_qkv8<<<450, 512, 0, stream>>>(Xb, Wqb, q_bias, v_bias, QKVb);

    dim3 ga(4, NHEADS, BATCH);
    attn<<<ga, 256, 0, stream>>>(QKVb, biasm, Ob);

    gemm_proj<<<594, 256, 0, stream>>>(Ob, Wpb, proj_b, out);
}

// Round 6
// 189.950 us; speedup vs baseline: 1.7872x; 1.0367x over previous
//
#include <hip/hip_runtime.h>
#include <hip/hip_bf16.h>

#define DIM 768
#define NHEADS 12
#define HD 64
#define NTOK 197
#define BATCH 64
#define NTOKENS (BATCH*NTOK)          // 12608
#define NPAIR (NTOK*NTOK)             // 38809
#define QK_SCALE 0.125f               // 64^-0.5
#define CDIM 2304                     // qkv row width

typedef short bf16x8 __attribute__((ext_vector_type(8)));
typedef float f32x4 __attribute__((ext_vector_type(4)));

#define MFMA(a,b,c) __builtin_amdgcn_mfma_f32_16x16x32_bf16(a,b,c,0,0,0)

__device__ __forceinline__ unsigned short f2bf(float f) {
    union { float f; unsigned u; } v; v.f = f;
    unsigned r = v.u + 0x7FFFu + ((v.u >> 16) & 1u);
    return (unsigned short)(r >> 16);
}

__device__ __forceinline__ float bf2f(unsigned short u) {
    union { unsigned v; float f; } x; x.v = ((unsigned)u) << 16; return x.f;
}

__device__ __forceinline__ void gload16(const unsigned short* g, unsigned short* l) {
    __builtin_amdgcn_global_load_lds(
        (const __attribute__((address_space(1))) void*)g,
        (__attribute__((address_space(3))) void*)l, 16, 0, 0);
}

// bijective XCD-aware block swizzle (m204)
__device__ __forceinline__ int xcd_swz(int orig, int nwg) {
    int q = nwg >> 3, r = nwg & 7;
    int xcd = orig & 7, idx = orig >> 3;
    return (xcd < r ? xcd * (q + 1) : r * (q + 1) + (xcd - r) * q) + idx;
}

// ---------------- fp32 -> bf16 bulk convert (8 elems/thread)
__global__ __launch_bounds__(256) void to_bf16(const float* __restrict__ s,
                                               unsigned short* __restrict__ d, int n8) {
    int t = blockIdx.x * 256 + threadIdx.x;
    if (t >= n8) return;
    float4 a = ((const float4*)s)[t * 2], b = ((const float4*)s)[t * 2 + 1];
    union { unsigned short u[8]; bf16x8 v; } p;
    p.u[0] = f2bf(a.x); p.u[1] = f2bf(a.y); p.u[2] = f2bf(a.z); p.u[3] = f2bf(a.w);
    p.u[4] = f2bf(b.x); p.u[5] = f2bf(b.y); p.u[6] = f2bf(b.z); p.u[7] = f2bf(b.w);
    ((bf16x8*)d)[t] = p.v;
}

// ---------------- bias precompute (bf16): biasm[h][i][j] = rpb[rel[i*197+j]*12 + h]
__global__ __launch_bounds__(256) void bias_pre(const float* __restrict__ rpb,
                                                const int* __restrict__ rel,
                                                unsigned short* __restrict__ biasm) {
    int t = blockIdx.x * 256 + threadIdx.x;
    if (t >= NHEADS * NPAIR) return;
    int h = t / NPAIR, p = t - h * NPAIR;
    biasm[t] = f2bf(rpb[rel[p] * NHEADS + h]);
}

// ---------------- GEMM1: qkv[token][2304] = Xb @ Wb^T (+bias, Q pre-scaled)
#define NKT 12
#define BUFE 16384

__global__ __launch_bounds__(512, 2) void gemm_qkv8(
    const unsigned short* __restrict__ Xb, const unsigned short* __restrict__ Wb,
    const float* __restrict__ qbias, const float* __restrict__ vbias,
    unsigned short* __restrict__ QKVb)
{
    __shared__ __attribute__((aligned(16))) unsigned short AsF[2 * BUFE];
    __shared__ __attribute__((aligned(16))) unsigned short BsF[2 * BUFE];
    int tid = threadIdx.x, lane = tid & 63, wid = tid >> 6;
    int wr = wid >> 2, wc = wid & 3;
    int wg = xcd_swz(blockIdx.x, 450);
    int bx = wg % 50, by = wg / 50;           // consecutive wg share W-panel
    int m0 = bx * 256, n0 = by * 256;
    int r15 = lane & 15, hi = lane >> 4, sx = lane & 7;
    int sl0 = hi ^ sx, sl1 = (hi + 4) ^ sx;

    size_t asrc[4], bsrc[4];
    int adoff[4];
    #pragma unroll
    for (int i = 0; i < 4; ++i) {
        int c = i * 512 + tid;
        int row = c >> 3, s = c & 7, rr = row & 127, half = row >> 7;
        int slot = s ^ (rr & 7);
        int ar = m0 + row; if (ar >= NTOKENS) ar = NTOKENS - 1;
        asrc[i] = (size_t)ar * DIM + slot * 8;
        bsrc[i] = (size_t)(n0 + row) * DIM + slot * 8;
        adoff[i] = half * 8192 + rr * 64 + s * 8;
    }
    int abase0 = wr * 8192 + r15 * 64;
    int bbase0 = (wc >> 1) * 8192 + (wc & 1) * 4096 + r15 * 64;

    f32x4 acc[8][4];
    #pragma unroll
    for (int i = 0; i < 8; ++i)
        #pragma unroll
        for (int j = 0; j < 4; ++j) acc[i][j] = (f32x4){0.f, 0.f, 0.f, 0.f};

#define STAGE(buf, kt) do { \
    _Pragma("unroll") \
    for (int i = 0; i < 4; ++i) { \
        gload16(Xb + asrc[i] + (kt) * 64, &AsF[(buf) * BUFE + adoff[i]]); \
        gload16(Wb + bsrc[i] + (kt) * 64, &BsF[(buf) * BUFE + adoff[i]]); \
    } } while (0)

    bf16x8 af[4][2], bw[2][2];
#define PHASE(mh, nh, LA, LB, bo) do { \
    if (LA) { _Pragma("unroll") for (int mi = 0; mi < 4; ++mi) { \
        af[mi][0] = *(const bf16x8*)&AsF[(bo) + abase0 + ((mh)*4+mi)*1024 + sl0*8]; \
        af[mi][1] = *(const bf16x8*)&AsF[(bo) + abase0 + ((mh)*4+mi)*1024 + sl1*8]; } } \
    if (LB) { _Pragma("unroll") for (int ni = 0; ni < 2; ++ni) { \
        bw[ni][0] = *(const bf16x8*)&BsF[(bo) + bbase0 + ((nh)*2+ni)*1024 + sl0*8]; \
        bw[ni][1] = *(const bf16x8*)&BsF[(bo) + bbase0 + ((nh)*2+ni)*1024 + sl1*8]; } } \
    __builtin_amdgcn_s_setprio(1); \
    _Pragma("unroll") for (int mi = 0; mi < 4; ++mi) \
        _Pragma("unroll") for (int ni = 0; ni < 2; ++ni) { \
            acc[(mh)*4+mi][(nh)*2+ni] = MFMA(af[mi][0], bw[ni][0], acc[(mh)*4+mi][(nh)*2+ni]); \
            acc[(mh)*4+mi][(nh)*2+ni] = MFMA(af[mi][1], bw[ni][1], acc[(mh)*4+mi][(nh)*2+ni]); } \
    __builtin_amdgcn_s_setprio(0); \
} while (0)

    STAGE(0, 0);
    STAGE(1, 1);
    asm volatile("s_waitcnt vmcnt(8)" ::: "memory");
    __builtin_amdgcn_s_barrier();

    for (int t = 0; t < NKT; ++t) {
        int bo = (t & 1) * BUFE;
        PHASE(0, 0, 1, 1, bo);
        PHASE(0, 1, 0, 1, bo);
        PHASE(1, 1, 1, 0, bo);
        PHASE(1, 0, 0, 1, bo);
        __builtin_amdgcn_s_barrier();
        if (t + 2 < NKT) {
            STAGE(t & 1, t + 2);
            asm volatile("s_waitcnt vmcnt(8)" ::: "memory");
        } else {
            asm volatile("s_waitcnt vmcnt(0)" ::: "memory");
        }
        __builtin_amdgcn_s_barrier();
    }
#undef STAGE
#undef PHASE

    // epilogue: bias+scale in regs -> per-wave LDS transpose -> coalesced stores
    unsigned short* reg = (wid < 4) ? &AsF[wid * 8192] : &BsF[(wid - 4) * 8192];
    {
        int which = n0 / DIM;
        float scl = (which == 0) ? QK_SCALE : 1.f;
        #pragma unroll
        for (int n = 0; n < 4; ++n) {
            int colr = n0 - which * DIM + wc * 64 + n * 16 + r15;
            float bv = (which == 0) ? qbias[colr] : (which == 2 ? vbias[colr] : 0.f);
            #pragma unroll
            for (int m = 0; m < 8; ++m) {
                int lrb = m * 16 + hi * 4;
                #pragma unroll
                for (int r = 0; r < 4; ++r) {
                    int lr = lrb + r;
                    int c = n * 16 + r15;
                    reg[lr * 64 + (c ^ (((lr >> 2) & 3) << 4))] =
                        f2bf((acc[m][n][r] + bv) * scl);
                }
            }
        }
    }
    #pragma unroll
    for (int it = 0; it < 16; ++it) {
        int c = it * 64 + lane;
        int lr = c >> 3, cc = c & 7;
        int row = m0 + wr * 128 + lr;
        if (row < NTOKENS) {
            bf16x8 v = *(bf16x8*)&reg[lr * 64 + ((cc * 8) ^ (((lr >> 2) & 3) << 4))];
            *(bf16x8*)(QKVb + (size_t)row * CDIM + n0 + wc * 64 + cc * 8) = v;
        }
    }
}

// ---------------- fused attention: QKV[token][2304] in, O[token][768] out
// VT: bf16 [64 d][256], 16B-slot XOR swizzle slot^(d&7)^((d>>3)&7) -> 2-way max.
// P aliases dead K region. 61.2 KB LDS -> 2 blocks/CU.
#define KP 72          // Kl pitch (elems)
#define PP 232         // Pl pitch (elems), 464B rows (16B-aligned)
#define VPITCH 256     // VT pitch (elems) = 32 16B-slots

__global__ __launch_bounds__(256) void attn(
    const unsigned short* __restrict__ QKV, const unsigned short* __restrict__ biasm,
    unsigned short* __restrict__ O)
{
    __shared__ __attribute__((aligned(16))) unsigned short VT[64 * VPITCH];   // 32768 B
    __shared__ __attribute__((aligned(16))) unsigned short KlPl[208 * KP];    // 29952 B

    int tid = threadIdx.x, lane = tid & 63, wid = tid >> 6;
    int r15 = lane & 15, hi = lane >> 4;
    // dispatch remap: id = g*32 + qt*8 + p ; (b,h) = g*8+p -> same (b,h) q-tiles
    // sit 8 ids apart (same XCD under round-robin) and temporally adjacent.
    int wg = blockIdx.x;
    int g = wg >> 5, qt = (wg >> 3) & 3, p = wg & 7;
    int bh = g * 8 + p;
    int h = bh % NHEADS, b = bh / NHEADS;
    size_t tb = (size_t)b * NTOK;
    int hq = h * 64;

    // T14: V loads into regs up front (latency hides under K staging + QK^T)
    bf16x8 v0r[4], v1r[4];
    #pragma unroll
    for (int it = 0; it < 4; ++it) {
        int c = it * 256 + tid;
        int rp = c >> 3, kc = c & 7;
        int r0 = 2 * rp, r1 = 2 * rp + 1;
        bf16x8 z = (bf16x8)(short)0;
        v0r[it] = z; v1r[it] = z;
        if (r0 < NTOK) v0r[it] = *(const bf16x8*)(QKV + (tb + r0) * CDIM + 1536 + hq + kc * 8);
        if (r1 < NTOK) v1r[it] = *(const bf16x8*)(QKV + (tb + r1) * CDIM + 1536 + hq + kc * 8);
    }

    // stage K rows
    #pragma unroll
    for (int t = 0; t < 7; ++t) {
        int c = t * 256 + tid;
        if (c < NTOK * 8) {
            int row = c >> 3, kc = c & 7;
            *(bf16x8*)&KlPl[row * KP + kc * 8] =
                *(const bf16x8*)(QKV + (tb + row) * CDIM + 768 + hq + kc * 8);
        }
    }
    __syncthreads();

    // Q fragments
    int qrow_g = qt * 64 + wid * 16 + r15;
    int qsrc = qrow_g < NTOK ? qrow_g : (NTOK - 1);
    bf16x8 aq[2];
    #pragma unroll
    for (int ks = 0; ks < 2; ++ks)
        aq[ks] = *(const bf16x8*)(QKV + (tb + qsrc) * CDIM + hq + ks * 32 + hi * 8);

    // S = Q K^T
    f32x4 sa[13];
    #pragma unroll
    for (int t = 0; t < 13; ++t) sa[t] = (f32x4){0.f,0.f,0.f,0.f};
    __builtin_amdgcn_s_setprio(1);
    #pragma unroll
    for (int t = 0; t < 13; ++t) {
        #pragma unroll
        for (int ks = 0; ks < 2; ++ks) {
            bf16x8 bk = *(bf16x8*)&KlPl[(t * 16 + r15) * KP + ks * 32 + hi * 8];
            sa[t] = MFMA(aq[ks], bk, sa[t]);
        }
    }
    __builtin_amdgcn_s_setprio(0);
    __syncthreads();          // all waves past QK^T: Kl region becomes Pl

    // V regs -> VT (swizzled): key pair (2rp,2rp+1) of row d=kc*8+j goes to
    // elem d*256 + ((rp>>2)^j^kc)*8 + (rp&3)*2  (2-way banked writes)
    #pragma unroll
    for (int it = 0; it < 4; ++it) {
        int c = it * 256 + tid;
        int rp = c >> 3, kc = c & 7;
        if (rp < 112) {
            #pragma unroll
            for (int j = 0; j < 8; ++j) {
                unsigned int w = (unsigned int)(unsigned short)v0r[it][j] |
                                 ((unsigned int)(unsigned short)v1r[it][j] << 16);
                int slot2 = (rp >> 2) ^ j ^ kc;
                *(unsigned int*)&VT[(kc * 8 + j) * VPITCH + slot2 * 8 + (rp & 3) * 2] = w;
            }
        }
    }

    // softmax -> P (bf16) into KlPl region (bias loads bf16)
    int plbase = wid * (16 * PP);
    int rbase = qt * 64 + wid * 16 + hi * 4;
    #pragma unroll
    for (int r = 0; r < 4; ++r) {
        int row_g = rbase + r;
        int rowc = row_g < NTOK ? row_g : (NTOK - 1);
        const unsigned short* brow = biasm + h * NPAIR + rowc * NTOK;
        #pragma unroll
        for (int t = 0; t < 13; ++t) {
            int col = t * 16 + r15;
            if (col < NTOK) sa[t][r] += bf2f(brow[col]);
            else            sa[t][r] = -1e30f;
        }
        float mx = sa[0][r];
        #pragma unroll
        for (int t = 1; t < 13; ++t) mx = fmaxf(mx, sa[t][r]);
        #pragma unroll
        for (int m = 1; m < 16; m <<= 1) mx = fmaxf(mx, __shfl_xor(mx, m));
        float sum = 0.f;
        #pragma unroll
        for (int t = 0; t < 13; ++t) {
            float e = __expf(sa[t][r] - mx);
            sa[t][r] = e; sum += e;
        }
        #pragma unroll
        for (int m = 1; m < 16; m <<= 1) sum += __shfl_xor(sum, m);
        float inv = 1.f / sum;
        int roff = plbase + (hi * 4 + r) * PP;
        #pragma unroll
        for (int t = 0; t < 13; ++t)
            KlPl[roff + t * 16 + r15] = f2bf(sa[t][r] * inv);
        KlPl[roff + 208 + r15] = 0;
    }
    __syncthreads();          // VT fully written

    // O = P V ; V^T frags via single b128 per (dt,ks) from swizzled VT
    f32x4 oa[4];
    #pragma unroll
    for (int dt = 0; dt < 4; ++dt) oa[dt] = (f32x4){0.f,0.f,0.f,0.f};
    int X = hi ^ (r15 & 7) ^ (r15 >> 3);
    __builtin_amdgcn_s_setprio(1);
    #pragma unroll
    for (int ks = 0; ks < 7; ++ks) {
        bf16x8 ap = *(bf16x8*)&KlPl[plbase + r15 * PP + ks * 32 + hi * 8];
        #pragma unroll
        for (int dt = 0; dt < 4; ++dt) {
            int d = dt * 16 + r15;
            int slotp = (ks * 4) ^ (dt * 2) ^ X;
            bf16x8 bv = *(bf16x8*)&VT[d * VPITCH + slotp * 8];
            oa[dt] = MFMA(ap, bv, oa[dt]);
        }
    }
    __builtin_amdgcn_s_setprio(0);

    // O write via per-wave LDS transpose (own Pl region, pitch 72) -> 16B stores
    #pragma unroll
    for (int dt = 0; dt < 4; ++dt)
        #pragma unroll
        for (int r = 0; r < 4; ++r)
            KlPl[plbase + (hi * 4 + r) * 72 + dt * 16 + r15] = f2bf(oa[dt][r]);
    #pragma unroll
    for (int it = 0; it < 2; ++it) {
        int c = it * 64 + lane;
        int lr = c >> 3, cc = c & 7;
        int qrow = qt * 64 + wid * 16 + lr;
        if (qrow < NTOK)
            *(bf16x8*)(O + (tb + qrow) * DIM + hq + cc * 8) =
                *(bf16x8*)&KlPl[plbase + lr * 72 + cc * 8];
    }
}

// ---------------- GEMM2: out = O @ Wp^T + proj_b (fp32 out)
__global__ __launch_bounds__(256) void gemm_proj(
    const unsigned short* __restrict__ Ob, const unsigned short* __restrict__ Wp,
    const float* __restrict__ pbias, float* __restrict__ out)
{
    __shared__ __attribute__((aligned(16))) unsigned short As[128 * 64];
    __shared__ __attribute__((aligned(16))) unsigned short Bs[128 * 64];
    int tid = threadIdx.x, lane = tid & 63, wid = tid >> 6;
    int wg = xcd_swz(blockIdx.x, 594);
    int bx = wg % 99, by = wg / 99;
    int m0 = bx * 128, n0 = by * 128;
    int wm = (wid >> 1) * 64, wn = (wid & 1) * 64;

    size_t abase[4], bbase[4];
    unsigned short *alds[4], *blds[4];
    #pragma unroll
    for (int i = 0; i < 4; ++i) {
        int chunk = i * 4 + wid;
        int row = chunk * 8 + (lane >> 3);
        int slot = (lane & 7) ^ (row & 7);
        int ar = m0 + row; if (ar >= NTOKENS) ar = NTOKENS - 1;
        abase[i] = (size_t)ar * DIM + slot * 8;
        bbase[i] = (size_t)(n0 + row) * DIM + slot * 8;
        alds[i] = &As[chunk * 512];
        blds[i] = &Bs[chunk * 512];
    }
    int r15 = lane & 15, hi = lane >> 4, sx = lane & 7;
    int s0 = (hi ^ sx) * 8, s1 = ((hi + 4) ^ sx) * 8;
    int arow[4], brow[4];
    #pragma unroll
    for (int i = 0; i < 4; ++i) {
        arow[i] = (wm + i * 16 + r15) * 64;
        brow[i] = (wn + i * 16 + r15) * 64;
    }

    f32x4 acc[4][4];
    #pragma unroll
    for (int i = 0; i < 4; ++i)
        #pragma unroll
        for (int j = 0; j < 4; ++j) acc[i][j] = (f32x4){0.f, 0.f, 0.f, 0.f};

    for (int k0 = 0; k0 < DIM; k0 += 64) {
        __syncthreads();
        #pragma unroll
        for (int i = 0; i < 4; ++i) {
            gload16(Ob + abase[i] + k0, alds[i]);
            gload16(Wp + bbase[i] + k0, blds[i]);
        }
        __syncthreads();
        #pragma unroll
        for (int ks = 0; ks < 2; ++ks) {
            int so = ks ? s1 : s0;
            bf16x8 af[4], bw[4];
            #pragma unroll
            for (int i = 0; i < 4; ++i) af[i] = *(bf16x8*)&As[arow[i] + so];
            #pragma unroll
            for (int j = 0; j < 4; ++j) bw[j] = *(bf16x8*)&Bs[brow[j] + so];
            #pragma unroll
            for (int i = 0; i < 4; ++i)
                #pragma unroll
                for (int j = 0; j < 4; ++j)
                    acc[i][j] = MFMA(af[i], bw[j], acc[i][j]);
        }
    }

    #pragma unroll
    for (int j = 0; j < 4; ++j) {
        int col = n0 + wn + j * 16 + r15;
        float bv = pbias[col];
        #pragma unroll
        for (int i = 0; i < 4; ++i) {
            #pragma unroll
            for (int r = 0; r < 4; ++r) {
                int row = m0 + wm + i * 16 + hi * 4 + r;
                if (row < NTOKENS)
                    out[(size_t)row * DIM + col] = acc[i][j][r] + bv;
            }
        }
    }
}

extern "C" void kernel_launch(void* const* d_in, const int* in_sizes, int n_in,
                              void* d_out, int out_size, void* d_ws, size_t ws_size,
                              hipStream_t stream) {
    const float* x      = (const float*)d_in[0];
    const float* qkv_w  = (const float*)d_in[1];
    const float* q_bias = (const float*)d_in[2];
    const float* v_bias = (const float*)d_in[3];
    const float* rpb    = (const float*)d_in[4];
    const float* proj_w = (const float*)d_in[5];
    const float* proj_b = (const float*)d_in[6];
    const int*   rel    = (const int*)d_in[7];
    float* out = (float*)d_out;

    const size_t NELEM = (size_t)NTOKENS * DIM;      // 9,682,944
    const size_t WQKV  = (size_t)3 * DIM * DIM;
    const size_t WPROJ = (size_t)DIM * DIM;
    unsigned short* Xb   = (unsigned short*)d_ws;    // reused as Ob after gemm_qkv8
    unsigned short* Wqb  = Xb + NELEM;
    unsigned short* Wpb  = Wqb + WQKV;
    unsigned short* QKVb = Wpb + WPROJ;              // [12608][2304]
    unsigned short* biasm = QKVb + (size_t)NTOKENS * CDIM;   // bf16 [12][197][197]
    unsigned short* Ob = Xb;

    to_bf16<<<(int)((NELEM / 8 + 255) / 256), 256, 0, stream>>>(x, Xb, (int)(NELEM / 8));
    to_bf16<<<(int)((WQKV / 8 + 255) / 256), 256, 0, stream>>>(qkv_w, Wqb, (int)(WQKV / 8));
    to_bf16<<<(int)((WPROJ / 8 + 255) / 256), 256, 0, stream>>>(proj_w, Wpb, (int)(WPROJ / 8));
    bias_pre<<<(NHEADS * NPAIR + 255) / 256, 256, 0, stream>>>(rpb, rel, biasm);

    gemm_qkv8<<<450, 512, 0, stream>>>(Xb, Wqb, q_bias, v_bias, QKVb);

    attn<<<3072, 256, 0, stream>>>(QKVb, biasm, Ob);

    gemm_proj<<<594, 256, 0, stream>>>(Ob, Wpb, proj_b, out);
}

// Round 7
// 181.360 us; speedup vs baseline: 1.8719x; 1.0474x over previous
//
#include <hip/hip_runtime.h>
#include <hip/hip_bf16.h>

#define DIM 768
#define NHEADS 12
#define HD 64
#define NTOK 197
#define BATCH 64
#define NTOKENS (BATCH*NTOK)          // 12608
#define NPAIR (NTOK*NTOK)             // 38809
#define QK_SCALE 0.125f               // 64^-0.5
#define CDIM 2304                     // qkv row width

typedef short bf16x8 __attribute__((ext_vector_type(8)));
typedef float f32x4 __attribute__((ext_vector_type(4)));

#define MFMA(a,b,c) __builtin_amdgcn_mfma_f32_16x16x32_bf16(a,b,c,0,0,0)

__device__ __forceinline__ unsigned short f2bf(float f) {
    union { float f; unsigned u; } v; v.f = f;
    unsigned r = v.u + 0x7FFFu + ((v.u >> 16) & 1u);
    return (unsigned short)(r >> 16);
}

__device__ __forceinline__ float bf2f(unsigned short u) {
    union { unsigned v; float f; } x; x.v = ((unsigned)u) << 16; return x.f;
}

__device__ __forceinline__ void gload16(const unsigned short* g, unsigned short* l) {
    __builtin_amdgcn_global_load_lds(
        (const __attribute__((address_space(1))) void*)g,
        (__attribute__((address_space(3))) void*)l, 16, 0, 0);
}

// bijective XCD-aware block swizzle (m204)
__device__ __forceinline__ int xcd_swz(int orig, int nwg) {
    int q = nwg >> 3, r = nwg & 7;
    int xcd = orig & 7, idx = orig >> 3;
    return (xcd < r ? xcd * (q + 1) : r * (q + 1) + (xcd - r) * q) + idx;
}

// ---------------- fp32 -> bf16 bulk convert (8 elems/thread)
__global__ __launch_bounds__(256) void to_bf16(const float* __restrict__ s,
                                               unsigned short* __restrict__ d, int n8) {
    int t = blockIdx.x * 256 + threadIdx.x;
    if (t >= n8) return;
    float4 a = ((const float4*)s)[t * 2], b = ((const float4*)s)[t * 2 + 1];
    union { unsigned short u[8]; bf16x8 v; } p;
    p.u[0] = f2bf(a.x); p.u[1] = f2bf(a.y); p.u[2] = f2bf(a.z); p.u[3] = f2bf(a.w);
    p.u[4] = f2bf(b.x); p.u[5] = f2bf(b.y); p.u[6] = f2bf(b.z); p.u[7] = f2bf(b.w);
    ((bf16x8*)d)[t] = p.v;
}

// ---------------- bias precompute (bf16): biasm[h][i][j] = rpb[rel[i*197+j]*12 + h]
__global__ __launch_bounds__(256) void bias_pre(const float* __restrict__ rpb,
                                                const int* __restrict__ rel,
                                                unsigned short* __restrict__ biasm) {
    int t = blockIdx.x * 256 + threadIdx.x;
    if (t >= NHEADS * NPAIR) return;
    int h = t / NPAIR, p = t - h * NPAIR;
    biasm[t] = f2bf(rpb[rel[p] * NHEADS + h]);
}

// ---------------- GEMM1: qkv[token][2304] = Xb @ Wb^T (+bias, Q pre-scaled)
#define NKT 12
#define BUFE 16384

__global__ __launch_bounds__(512, 2) void gemm_qkv8(
    const unsigned short* __restrict__ Xb, const unsigned short* __restrict__ Wb,
    const float* __restrict__ qbias, const float* __restrict__ vbias,
    unsigned short* __restrict__ QKVb)
{
    __shared__ __attribute__((aligned(16))) unsigned short AsF[2 * BUFE];
    __shared__ __attribute__((aligned(16))) unsigned short BsF[2 * BUFE];
    int tid = threadIdx.x, lane = tid & 63, wid = tid >> 6;
    int wr = wid >> 2, wc = wid & 3;
    int wg = xcd_swz(blockIdx.x, 450);
    int bx = wg / 9, by = wg % 9;             // consecutive wg share X-panel
    int m0 = bx * 256, n0 = by * 256;
    int r15 = lane & 15, hi = lane >> 4, sx = lane & 7;
    int sl0 = hi ^ sx, sl1 = (hi + 4) ^ sx;

    size_t asrc[4], bsrc[4];
    int adoff[4];
    #pragma unroll
    for (int i = 0; i < 4; ++i) {
        int c = i * 512 + tid;
        int row = c >> 3, s = c & 7, rr = row & 127, half = row >> 7;
        int slot = s ^ (rr & 7);
        int ar = m0 + row; if (ar >= NTOKENS) ar = NTOKENS - 1;
        asrc[i] = (size_t)ar * DIM + slot * 8;
        bsrc[i] = (size_t)(n0 + row) * DIM + slot * 8;
        adoff[i] = half * 8192 + rr * 64 + s * 8;
    }
    int abase0 = wr * 8192 + r15 * 64;
    int bbase0 = (wc >> 1) * 8192 + (wc & 1) * 4096 + r15 * 64;

    f32x4 acc[8][4];
    #pragma unroll
    for (int i = 0; i < 8; ++i)
        #pragma unroll
        for (int j = 0; j < 4; ++j) acc[i][j] = (f32x4){0.f, 0.f, 0.f, 0.f};

#define STAGE(buf, kt) do { \
    _Pragma("unroll") \
    for (int i = 0; i < 4; ++i) { \
        gload16(Xb + asrc[i] + (kt) * 64, &AsF[(buf) * BUFE + adoff[i]]); \
        gload16(Wb + bsrc[i] + (kt) * 64, &BsF[(buf) * BUFE + adoff[i]]); \
    } } while (0)

    bf16x8 af[4][2], bw[2][2];
#define PHASE(mh, nh, LA, LB, bo) do { \
    if (LA) { _Pragma("unroll") for (int mi = 0; mi < 4; ++mi) { \
        af[mi][0] = *(const bf16x8*)&AsF[(bo) + abase0 + ((mh)*4+mi)*1024 + sl0*8]; \
        af[mi][1] = *(const bf16x8*)&AsF[(bo) + abase0 + ((mh)*4+mi)*1024 + sl1*8]; } } \
    if (LB) { _Pragma("unroll") for (int ni = 0; ni < 2; ++ni) { \
        bw[ni][0] = *(const bf16x8*)&BsF[(bo) + bbase0 + ((nh)*2+ni)*1024 + sl0*8]; \
        bw[ni][1] = *(const bf16x8*)&BsF[(bo) + bbase0 + ((nh)*2+ni)*1024 + sl1*8]; } } \
    __builtin_amdgcn_s_setprio(1); \
    _Pragma("unroll") for (int mi = 0; mi < 4; ++mi) \
        _Pragma("unroll") for (int ni = 0; ni < 2; ++ni) { \
            acc[(mh)*4+mi][(nh)*2+ni] = MFMA(af[mi][0], bw[ni][0], acc[(mh)*4+mi][(nh)*2+ni]); \
            acc[(mh)*4+mi][(nh)*2+ni] = MFMA(af[mi][1], bw[ni][1], acc[(mh)*4+mi][(nh)*2+ni]); } \
    __builtin_amdgcn_s_setprio(0); \
} while (0)

    STAGE(0, 0);
    STAGE(1, 1);
    asm volatile("s_waitcnt vmcnt(8)" ::: "memory");
    __builtin_amdgcn_s_barrier();

    for (int t = 0; t < NKT; ++t) {
        int bo = (t & 1) * BUFE;
        PHASE(0, 0, 1, 1, bo);
        PHASE(0, 1, 0, 1, bo);
        PHASE(1, 1, 1, 0, bo);
        PHASE(1, 0, 0, 1, bo);
        __builtin_amdgcn_s_barrier();
        if (t + 2 < NKT) {
            STAGE(t & 1, t + 2);
            asm volatile("s_waitcnt vmcnt(8)" ::: "memory");
        } else {
            asm volatile("s_waitcnt vmcnt(0)" ::: "memory");
        }
        __builtin_amdgcn_s_barrier();
    }

    // epilogue: bias+scale in regs -> per-wave LDS transpose -> coalesced stores
    unsigned short* reg = (wid < 4) ? &AsF[wid * 8192] : &BsF[(wid - 4) * 8192];
    {
        int which = n0 / DIM;
        float scl = (which == 0) ? QK_SCALE : 1.f;
        #pragma unroll
        for (int n = 0; n < 4; ++n) {
            int colr = n0 - which * DIM + wc * 64 + n * 16 + r15;
            float bv = (which == 0) ? qbias[colr] : (which == 2 ? vbias[colr] : 0.f);
            #pragma unroll
            for (int m = 0; m < 8; ++m) {
                int lrb = m * 16 + hi * 4;
                #pragma unroll
                for (int r = 0; r < 4; ++r) {
                    int lr = lrb + r;
                    int c = n * 16 + r15;
                    reg[lr * 64 + (c ^ (((lr >> 2) & 3) << 4))] =
                        f2bf((acc[m][n][r] + bv) * scl);
                }
            }
        }
    }
    #pragma unroll
    for (int it = 0; it < 16; ++it) {
        int c = it * 64 + lane;
        int lr = c >> 3, cc = c & 7;
        int row = m0 + wr * 128 + lr;
        if (row < NTOKENS) {
            bf16x8 v = *(bf16x8*)&reg[lr * 64 + ((cc * 8) ^ (((lr >> 2) & 3) << 4))];
            *(bf16x8*)(QKVb + (size_t)row * CDIM + n0 + wc * 64 + cc * 8) = v;
        }
    }
#undef STAGE
#undef PHASE
}

// ---------------- GEMM2: out = O @ Wp^T + proj_b (fp32), 8-phase 256^2 pipeline
__global__ __launch_bounds__(512, 2) void gemm_proj8(
    const unsigned short* __restrict__ Ob, const unsigned short* __restrict__ Wp,
    const float* __restrict__ pbias, float* __restrict__ out)
{
    __shared__ __attribute__((aligned(16))) unsigned short AsF[2 * BUFE];
    __shared__ __attribute__((aligned(16))) unsigned short BsF[2 * BUFE];
    int tid = threadIdx.x, lane = tid & 63, wid = tid >> 6;
    int wr = wid >> 2, wc = wid & 3;
    int wg = xcd_swz(blockIdx.x, 150);
    int bx = wg / 3, by = wg % 3;             // consecutive wg share A-panel
    int m0 = bx * 256, n0 = by * 256;
    int r15 = lane & 15, hi = lane >> 4, sx = lane & 7;
    int sl0 = hi ^ sx, sl1 = (hi + 4) ^ sx;

    size_t asrc[4], bsrc[4];
    int adoff[4];
    #pragma unroll
    for (int i = 0; i < 4; ++i) {
        int c = i * 512 + tid;
        int row = c >> 3, s = c & 7, rr = row & 127, half = row >> 7;
        int slot = s ^ (rr & 7);
        int ar = m0 + row; if (ar >= NTOKENS) ar = NTOKENS - 1;
        asrc[i] = (size_t)ar * DIM + slot * 8;
        bsrc[i] = (size_t)(n0 + row) * DIM + slot * 8;
        adoff[i] = half * 8192 + rr * 64 + s * 8;
    }
    int abase0 = wr * 8192 + r15 * 64;
    int bbase0 = (wc >> 1) * 8192 + (wc & 1) * 4096 + r15 * 64;

    f32x4 acc[8][4];
    #pragma unroll
    for (int i = 0; i < 8; ++i)
        #pragma unroll
        for (int j = 0; j < 4; ++j) acc[i][j] = (f32x4){0.f, 0.f, 0.f, 0.f};

#define STAGE(buf, kt) do { \
    _Pragma("unroll") \
    for (int i = 0; i < 4; ++i) { \
        gload16(Ob + asrc[i] + (kt) * 64, &AsF[(buf) * BUFE + adoff[i]]); \
        gload16(Wp + bsrc[i] + (kt) * 64, &BsF[(buf) * BUFE + adoff[i]]); \
    } } while (0)

    bf16x8 af[4][2], bw[2][2];
#define PHASE(mh, nh, LA, LB, bo) do { \
    if (LA) { _Pragma("unroll") for (int mi = 0; mi < 4; ++mi) { \
        af[mi][0] = *(const bf16x8*)&AsF[(bo) + abase0 + ((mh)*4+mi)*1024 + sl0*8]; \
        af[mi][1] = *(const bf16x8*)&AsF[(bo) + abase0 + ((mh)*4+mi)*1024 + sl1*8]; } } \
    if (LB) { _Pragma("unroll") for (int ni = 0; ni < 2; ++ni) { \
        bw[ni][0] = *(const bf16x8*)&BsF[(bo) + bbase0 + ((nh)*2+ni)*1024 + sl0*8]; \
        bw[ni][1] = *(const bf16x8*)&BsF[(bo) + bbase0 + ((nh)*2+ni)*1024 + sl1*8]; } } \
    __builtin_amdgcn_s_setprio(1); \
    _Pragma("unroll") for (int mi = 0; mi < 4; ++mi) \
        _Pragma("unroll") for (int ni = 0; ni < 2; ++ni) { \
            acc[(mh)*4+mi][(nh)*2+ni] = MFMA(af[mi][0], bw[ni][0], acc[(mh)*4+mi][(nh)*2+ni]); \
            acc[(mh)*4+mi][(nh)*2+ni] = MFMA(af[mi][1], bw[ni][1], acc[(mh)*4+mi][(nh)*2+ni]); } \
    __builtin_amdgcn_s_setprio(0); \
} while (0)

    STAGE(0, 0);
    STAGE(1, 1);
    asm volatile("s_waitcnt vmcnt(8)" ::: "memory");
    __builtin_amdgcn_s_barrier();

    for (int t = 0; t < NKT; ++t) {
        int bo = (t & 1) * BUFE;
        PHASE(0, 0, 1, 1, bo);
        PHASE(0, 1, 0, 1, bo);
        PHASE(1, 1, 1, 0, bo);
        PHASE(1, 0, 0, 1, bo);
        __builtin_amdgcn_s_barrier();
        if (t + 2 < NKT) {
            STAGE(t & 1, t + 2);
            asm volatile("s_waitcnt vmcnt(8)" ::: "memory");
        } else {
            asm volatile("s_waitcnt vmcnt(0)" ::: "memory");
        }
        __builtin_amdgcn_s_barrier();
    }
#undef STAGE
#undef PHASE

    // epilogue: fp32 out, 64B-contiguous per 16-lane group
    #pragma unroll
    for (int n = 0; n < 4; ++n) {
        int col = n0 + wc * 64 + n * 16 + r15;
        float bv = pbias[col];
        #pragma unroll
        for (int m = 0; m < 8; ++m) {
            #pragma unroll
            for (int r = 0; r < 4; ++r) {
                int row = m0 + wr * 128 + m * 16 + hi * 4 + r;
                if (row < NTOKENS)
                    out[(size_t)row * DIM + col] = acc[m][n][r] + bv;
            }
        }
    }
}

// ---------------- fused attention: QKV[token][2304] in, O[token][768] out
#define KP 72          // Kl pitch (elems)
#define PP 232         // Pl pitch (elems), 464B rows (16B-aligned)
#define VPITCH 256     // VT pitch (elems) = 32 16B-slots

__global__ __launch_bounds__(256) void attn(
    const unsigned short* __restrict__ QKV, const unsigned short* __restrict__ biasm,
    unsigned short* __restrict__ O)
{
    __shared__ __attribute__((aligned(16))) unsigned short VT[64 * VPITCH];   // 32768 B
    __shared__ __attribute__((aligned(16))) unsigned short KlPl[208 * KP];    // 29952 B

    int tid = threadIdx.x, lane = tid & 63, wid = tid >> 6;
    int r15 = lane & 15, hi = lane >> 4;
    int wg = blockIdx.x;
    int g = wg >> 5, qt = (wg >> 3) & 3, p = wg & 7;
    int bh = g * 8 + p;
    int h = bh % NHEADS, b = bh / NHEADS;
    size_t tb = (size_t)b * NTOK;
    int hq = h * 64;

    // T14: V loads into regs up front (latency hides under K staging + QK^T)
    bf16x8 v0r[4], v1r[4];
    #pragma unroll
    for (int it = 0; it < 4; ++it) {
        int c = it * 256 + tid;
        int rp = c >> 3, kc = c & 7;
        int r0 = 2 * rp, r1 = 2 * rp + 1;
        bf16x8 z = (bf16x8)(short)0;
        v0r[it] = z; v1r[it] = z;
        if (r0 < NTOK) v0r[it] = *(const bf16x8*)(QKV + (tb + r0) * CDIM + 1536 + hq + kc * 8);
        if (r1 < NTOK) v1r[it] = *(const bf16x8*)(QKV + (tb + r1) * CDIM + 1536 + hq + kc * 8);
    }

    // stage K rows
    #pragma unroll
    for (int t = 0; t < 7; ++t) {
        int c = t * 256 + tid;
        if (c < NTOK * 8) {
            int row = c >> 3, kc = c & 7;
            *(bf16x8*)&KlPl[row * KP + kc * 8] =
                *(const bf16x8*)(QKV + (tb + row) * CDIM + 768 + hq + kc * 8);
        }
    }
    __syncthreads();

    // Q fragments
    int qrow_g = qt * 64 + wid * 16 + r15;
    int qsrc = qrow_g < NTOK ? qrow_g : (NTOK - 1);
    bf16x8 aq[2];
    #pragma unroll
    for (int ks = 0; ks < 2; ++ks)
        aq[ks] = *(const bf16x8*)(QKV + (tb + qsrc) * CDIM + hq + ks * 32 + hi * 8);

    // S = Q K^T
    f32x4 sa[13];
    #pragma unroll
    for (int t = 0; t < 13; ++t) sa[t] = (f32x4){0.f,0.f,0.f,0.f};
    __builtin_amdgcn_s_setprio(1);
    #pragma unroll
    for (int t = 0; t < 13; ++t) {
        #pragma unroll
        for (int ks = 0; ks < 2; ++ks) {
            bf16x8 bk = *(bf16x8*)&KlPl[(t * 16 + r15) * KP + ks * 32 + hi * 8];
            sa[t] = MFMA(aq[ks], bk, sa[t]);
        }
    }
    __builtin_amdgcn_s_setprio(0);
    __syncthreads();          // all waves past QK^T: Kl region becomes Pl

    // V regs -> VT (swizzled)
    #pragma unroll
    for (int it = 0; it < 4; ++it) {
        int c = it * 256 + tid;
        int rp = c >> 3, kc = c & 7;
        if (rp < 112) {
            #pragma unroll
            for (int j = 0; j < 8; ++j) {
                unsigned int w = (unsigned int)(unsigned short)v0r[it][j] |
                                 ((unsigned int)(unsigned short)v1r[it][j] << 16);
                int slot2 = (rp >> 2) ^ j ^ kc;
                *(unsigned int*)&VT[(kc * 8 + j) * VPITCH + slot2 * 8 + (rp & 3) * 2] = w;
            }
        }
    }

    // softmax -> P (bf16) into KlPl region
    int plbase = wid * (16 * PP);
    int rbase = qt * 64 + wid * 16 + hi * 4;
    #pragma unroll
    for (int r = 0; r < 4; ++r) {
        int row_g = rbase + r;
        int rowc = row_g < NTOK ? row_g : (NTOK - 1);
        const unsigned short* brow = biasm + h * NPAIR + rowc * NTOK;
        #pragma unroll
        for (int t = 0; t < 13; ++t) {
            int col = t * 16 + r15;
            if (col < NTOK) sa[t][r] += bf2f(brow[col]);
            else            sa[t][r] = -1e30f;
        }
        float mx = sa[0][r];
        #pragma unroll
        for (int t = 1; t < 13; ++t) mx = fmaxf(mx, sa[t][r]);
        #pragma unroll
        for (int m = 1; m < 16; m <<= 1) mx = fmaxf(mx, __shfl_xor(mx, m));
        float sum = 0.f;
        #pragma unroll
        for (int t = 0; t < 13; ++t) {
            float e = __expf(sa[t][r] - mx);
            sa[t][r] = e; sum += e;
        }
        #pragma unroll
        for (int m = 1; m < 16; m <<= 1) sum += __shfl_xor(sum, m);
        float inv = 1.f / sum;
        int roff = plbase + (hi * 4 + r) * PP;
        #pragma unroll
        for (int t = 0; t < 13; ++t)
            KlPl[roff + t * 16 + r15] = f2bf(sa[t][r] * inv);
        KlPl[roff + 208 + r15] = 0;
    }
    __syncthreads();          // VT fully written

    // O = P V ; V^T frags via single b128 per (dt,ks) from swizzled VT
    f32x4 oa[4];
    #pragma unroll
    for (int dt = 0; dt < 4; ++dt) oa[dt] = (f32x4){0.f,0.f,0.f,0.f};
    int X = hi ^ (r15 & 7) ^ (r15 >> 3);
    __builtin_amdgcn_s_setprio(1);
    #pragma unroll
    for (int ks = 0; ks < 7; ++ks) {
        bf16x8 ap = *(bf16x8*)&KlPl[plbase + r15 * PP + ks * 32 + hi * 8];
        #pragma unroll
        for (int dt = 0; dt < 4; ++dt) {
            int d = dt * 16 + r15;
            int slotp = (ks * 4) ^ (dt * 2) ^ X;
            bf16x8 bv = *(bf16x8*)&VT[d * VPITCH + slotp * 8];
            oa[dt] = MFMA(ap, bv, oa[dt]);
        }
    }
    __builtin_amdgcn_s_setprio(0);

    // O write via per-wave LDS transpose -> 16B stores
    #pragma unroll
    for (int dt = 0; dt < 4; ++dt)
        #pragma unroll
        for (int r = 0; r < 4; ++r)
            KlPl[plbase + (hi * 4 + r) * 72 + dt * 16 + r15] = f2bf(oa[dt][r]);
    #pragma unroll
    for (int it = 0; it < 2; ++it) {
        int c = it * 64 + lane;
        int lr = c >> 3, cc = c & 7;
        int qrow = qt * 64 + wid * 16 + lr;
        if (qrow < NTOK)
            *(bf16x8*)(O + (tb + qrow) * DIM + hq + cc * 8) =
                *(bf16x8*)&KlPl[plbase + lr * 72 + cc * 8];
    }
}

extern "C" void kernel_launch(void* const* d_in, const int* in_sizes, int n_in,
                              void* d_out, int out_size, void* d_ws, size_t ws_size,
                              hipStream_t stream) {
    const float* x      = (const float*)d_in[0];
    const float* qkv_w  = (const float*)d_in[1];
    const float* q_bias = (const float*)d_in[2];
    const float* v_bias = (const float*)d_in[3];
    const float* rpb    = (const float*)d_in[4];
    const float* proj_w = (const float*)d_in[5];
    const float* proj_b = (const float*)d_in[6];
    const int*   rel    = (const int*)d_in[7];
    float* out = (float*)d_out;

    const size_t NELEM = (size_t)NTOKENS * DIM;      // 9,682,944
    const size_t WQKV  = (size_t)3 * DIM * DIM;
    const size_t WPROJ = (size_t)DIM * DIM;
    unsigned short* Xb   = (unsigned short*)d_ws;    // reused as Ob after gemm_qkv8
    unsigned short* Wqb  = Xb + NELEM;
    unsigned short* Wpb  = Wqb + WQKV;
    unsigned short* QKVb = Wpb + WPROJ;              // [12608][2304]
    unsigned short* biasm = QKVb + (size_t)NTOKENS * CDIM;   // bf16 [12][197][197]
    unsigned short* Ob = Xb;

    to_bf16<<<(int)((NELEM / 8 + 255) / 256), 256, 0, stream>>>(x, Xb, (int)(NELEM / 8));
    to_bf16<<<(int)((WQKV / 8 + 255) / 256), 256, 0, stream>>>(qkv_w, Wqb, (int)(WQKV / 8));
    to_bf16<<<(int)((WPROJ / 8 + 255) / 256), 256, 0, stream>>>(proj_w, Wpb, (int)(WPROJ / 8));
    bias_pre<<<(NHEADS * NPAIR + 255) / 256, 256, 0, stream>>>(rpb, rel, biasm);

    gemm_qkv8<<<450, 512, 0, stream>>>(Xb, Wqb, q_bias, v_bias, QKVb);

    attn<<<3072, 256, 0, stream>>>(QKVb, biasm, Ob);

    gemm_proj8<<<150, 512, 0, stream>>>(Ob, Wpb, proj_b, out);
}

// Round 8
// 165.541 us; speedup vs baseline: 2.0508x; 1.0956x over previous
//
#include <hip/hip_runtime.h>
#include <hip/hip_bf16.h>

#define DIM 768
#define NHEADS 12
#define HD 64
#define NTOK 197
#define BATCH 64
#define NTOKENS (BATCH*NTOK)          // 12608
#define NPAIR (NTOK*NTOK)             // 38809
#define QK_SCALE 0.125f               // 64^-0.5
#define CDIM 2304                     // qkv row width

typedef short bf16x8 __attribute__((ext_vector_type(8)));
typedef float f32x4 __attribute__((ext_vector_type(4)));

#define MFMA(a,b,c) __builtin_amdgcn_mfma_f32_16x16x32_bf16(a,b,c,0,0,0)

__device__ __forceinline__ unsigned short f2bf(float f) {
    union { float f; unsigned u; } v; v.f = f;
    unsigned r = v.u + 0x7FFFu + ((v.u >> 16) & 1u);
    return (unsigned short)(r >> 16);
}

__device__ __forceinline__ void gload16(const unsigned short* g, unsigned short* l) {
    __builtin_amdgcn_global_load_lds(
        (const __attribute__((address_space(1))) void*)g,
        (__attribute__((address_space(3))) void*)l, 16, 0, 0);
}

// bijective XCD-aware block swizzle (m204)
__device__ __forceinline__ int xcd_swz(int orig, int nwg) {
    int q = nwg >> 3, r = nwg & 7;
    int xcd = orig & 7, idx = orig >> 3;
    return (xcd < r ? xcd * (q + 1) : r * (q + 1) + (xcd - r) * q) + idx;
}

// ---------------- fused prep: 3x fp32->bf16 convert + bias gather (f32)
#define NB_X 4728     // NELEM/8/256
#define NB_WQ 864     // WQKV/8/256
#define NB_WP 288     // WPROJ/8/256
#define NB_BIAS 1820  // ceil(465708/256)

__device__ __forceinline__ void cvt8(const float* __restrict__ s,
                                     unsigned short* __restrict__ d, int t, int n8) {
    if (t >= n8) return;
    float4 a = ((const float4*)s)[t * 2], b = ((const float4*)s)[t * 2 + 1];
    union { unsigned short u[8]; bf16x8 v; } p;
    p.u[0] = f2bf(a.x); p.u[1] = f2bf(a.y); p.u[2] = f2bf(a.z); p.u[3] = f2bf(a.w);
    p.u[4] = f2bf(b.x); p.u[5] = f2bf(b.y); p.u[6] = f2bf(b.z); p.u[7] = f2bf(b.w);
    ((bf16x8*)d)[t] = p.v;
}

__global__ __launch_bounds__(256) void prep(
    const float* __restrict__ x, const float* __restrict__ qw,
    const float* __restrict__ pw, const float* __restrict__ rpb,
    const int* __restrict__ rel,
    unsigned short* __restrict__ Xb, unsigned short* __restrict__ Wqb,
    unsigned short* __restrict__ Wpb, float* __restrict__ biasm)
{
    int bid = blockIdx.x;
    if (bid < NB_X) {
        cvt8(x, Xb, bid * 256 + threadIdx.x, NB_X * 256);
    } else if (bid < NB_X + NB_WQ) {
        cvt8(qw, Wqb, (bid - NB_X) * 256 + threadIdx.x, NB_WQ * 256);
    } else if (bid < NB_X + NB_WQ + NB_WP) {
        cvt8(pw, Wpb, (bid - NB_X - NB_WQ) * 256 + threadIdx.x, NB_WP * 256);
    } else {
        int t = (bid - NB_X - NB_WQ - NB_WP) * 256 + threadIdx.x;
        if (t < NHEADS * NPAIR) {
            int h = t / NPAIR, p = t - h * NPAIR;
            biasm[t] = rpb[rel[p] * NHEADS + h];
        }
    }
}

// ---------------- GEMM1: qkv[token][2304] = Xb @ Wb^T (+bias, Q pre-scaled)
#define NKT 12
#define BUFE 16384

__global__ __launch_bounds__(512, 2) void gemm_qkv8(
    const unsigned short* __restrict__ Xb, const unsigned short* __restrict__ Wb,
    const float* __restrict__ qbias, const float* __restrict__ vbias,
    unsigned short* __restrict__ QKVb)
{
    __shared__ __attribute__((aligned(16))) unsigned short AsF[2 * BUFE];
    __shared__ __attribute__((aligned(16))) unsigned short BsF[2 * BUFE];
    int tid = threadIdx.x, lane = tid & 63, wid = tid >> 6;
    int wr = wid >> 2, wc = wid & 3;
    int wg = xcd_swz(blockIdx.x, 450);
    int bx = wg / 9, by = wg % 9;             // consecutive wg share X-panel
    int m0 = bx * 256, n0 = by * 256;
    int r15 = lane & 15, hi = lane >> 4, sx = lane & 7;
    int sl0 = hi ^ sx, sl1 = (hi + 4) ^ sx;

    size_t asrc[4], bsrc[4];
    int adoff[4];
    #pragma unroll
    for (int i = 0; i < 4; ++i) {
        int c = i * 512 + tid;
        int row = c >> 3, s = c & 7, rr = row & 127, half = row >> 7;
        int slot = s ^ (rr & 7);
        int ar = m0 + row; if (ar >= NTOKENS) ar = NTOKENS - 1;
        asrc[i] = (size_t)ar * DIM + slot * 8;
        bsrc[i] = (size_t)(n0 + row) * DIM + slot * 8;
        adoff[i] = half * 8192 + rr * 64 + s * 8;
    }
    int abase0 = wr * 8192 + r15 * 64;
    int bbase0 = (wc >> 1) * 8192 + (wc & 1) * 4096 + r15 * 64;

    f32x4 acc[8][4];
    #pragma unroll
    for (int i = 0; i < 8; ++i)
        #pragma unroll
        for (int j = 0; j < 4; ++j) acc[i][j] = (f32x4){0.f, 0.f, 0.f, 0.f};

#define STAGE(buf, kt) do { \
    _Pragma("unroll") \
    for (int i = 0; i < 4; ++i) { \
        gload16(Xb + asrc[i] + (kt) * 64, &AsF[(buf) * BUFE + adoff[i]]); \
        gload16(Wb + bsrc[i] + (kt) * 64, &BsF[(buf) * BUFE + adoff[i]]); \
    } } while (0)

    bf16x8 af[4][2], bw[2][2];
#define PHASE(mh, nh, LA, LB, bo) do { \
    if (LA) { _Pragma("unroll") for (int mi = 0; mi < 4; ++mi) { \
        af[mi][0] = *(const bf16x8*)&AsF[(bo) + abase0 + ((mh)*4+mi)*1024 + sl0*8]; \
        af[mi][1] = *(const bf16x8*)&AsF[(bo) + abase0 + ((mh)*4+mi)*1024 + sl1*8]; } } \
    if (LB) { _Pragma("unroll") for (int ni = 0; ni < 2; ++ni) { \
        bw[ni][0] = *(const bf16x8*)&BsF[(bo) + bbase0 + ((nh)*2+ni)*1024 + sl0*8]; \
        bw[ni][1] = *(const bf16x8*)&BsF[(bo) + bbase0 + ((nh)*2+ni)*1024 + sl1*8]; } } \
    __builtin_amdgcn_s_setprio(1); \
    _Pragma("unroll") for (int mi = 0; mi < 4; ++mi) \
        _Pragma("unroll") for (int ni = 0; ni < 2; ++ni) { \
            acc[(mh)*4+mi][(nh)*2+ni] = MFMA(af[mi][0], bw[ni][0], acc[(mh)*4+mi][(nh)*2+ni]); \
            acc[(mh)*4+mi][(nh)*2+ni] = MFMA(af[mi][1], bw[ni][1], acc[(mh)*4+mi][(nh)*2+ni]); } \
    __builtin_amdgcn_s_setprio(0); \
} while (0)

    STAGE(0, 0);
    STAGE(1, 1);
    asm volatile("s_waitcnt vmcnt(8)" ::: "memory");
    __builtin_amdgcn_s_barrier();

    for (int t = 0; t < NKT; ++t) {
        int bo = (t & 1) * BUFE;
        PHASE(0, 0, 1, 1, bo);
        PHASE(0, 1, 0, 1, bo);
        PHASE(1, 1, 1, 0, bo);
        PHASE(1, 0, 0, 1, bo);
        __builtin_amdgcn_s_barrier();
        if (t + 2 < NKT) {
            STAGE(t & 1, t + 2);
            asm volatile("s_waitcnt vmcnt(8)" ::: "memory");
        } else {
            asm volatile("s_waitcnt vmcnt(0)" ::: "memory");
        }
        __builtin_amdgcn_s_barrier();
    }

    // epilogue: bias+scale in regs -> per-wave LDS transpose -> coalesced stores
    unsigned short* reg = (wid < 4) ? &AsF[wid * 8192] : &BsF[(wid - 4) * 8192];
    {
        int which = n0 / DIM;
        float scl = (which == 0) ? QK_SCALE : 1.f;
        #pragma unroll
        for (int n = 0; n < 4; ++n) {
            int colr = n0 - which * DIM + wc * 64 + n * 16 + r15;
            float bv = (which == 0) ? qbias[colr] : (which == 2 ? vbias[colr] : 0.f);
            #pragma unroll
            for (int m = 0; m < 8; ++m) {
                int lrb = m * 16 + hi * 4;
                #pragma unroll
                for (int r = 0; r < 4; ++r) {
                    int lr = lrb + r;
                    int c = n * 16 + r15;
                    reg[lr * 64 + (c ^ (((lr >> 2) & 3) << 4))] =
                        f2bf((acc[m][n][r] + bv) * scl);
                }
            }
        }
    }
    #pragma unroll
    for (int it = 0; it < 16; ++it) {
        int c = it * 64 + lane;
        int lr = c >> 3, cc = c & 7;
        int row = m0 + wr * 128 + lr;
        if (row < NTOKENS) {
            bf16x8 v = *(bf16x8*)&reg[lr * 64 + ((cc * 8) ^ (((lr >> 2) & 3) << 4))];
            *(bf16x8*)(QKVb + (size_t)row * CDIM + n0 + wc * 64 + cc * 8) = v;
        }
    }
#undef STAGE
#undef PHASE
}

// ---------------- GEMM2: out = O @ Wp^T + proj_b (fp32), 8-phase 256^2 pipeline
__global__ __launch_bounds__(512, 2) void gemm_proj8(
    const unsigned short* __restrict__ Ob, const unsigned short* __restrict__ Wp,
    const float* __restrict__ pbias, float* __restrict__ out)
{
    __shared__ __attribute__((aligned(16))) unsigned short AsF[2 * BUFE];
    __shared__ __attribute__((aligned(16))) unsigned short BsF[2 * BUFE];
    int tid = threadIdx.x, lane = tid & 63, wid = tid >> 6;
    int wr = wid >> 2, wc = wid & 3;
    int wg = xcd_swz(blockIdx.x, 150);
    int bx = wg / 3, by = wg % 3;             // consecutive wg share A-panel
    int m0 = bx * 256, n0 = by * 256;
    int r15 = lane & 15, hi = lane >> 4, sx = lane & 7;
    int sl0 = hi ^ sx, sl1 = (hi + 4) ^ sx;

    size_t asrc[4], bsrc[4];
    int adoff[4];
    #pragma unroll
    for (int i = 0; i < 4; ++i) {
        int c = i * 512 + tid;
        int row = c >> 3, s = c & 7, rr = row & 127, half = row >> 7;
        int slot = s ^ (rr & 7);
        int ar = m0 + row; if (ar >= NTOKENS) ar = NTOKENS - 1;
        asrc[i] = (size_t)ar * DIM + slot * 8;
        bsrc[i] = (size_t)(n0 + row) * DIM + slot * 8;
        adoff[i] = half * 8192 + rr * 64 + s * 8;
    }
    int abase0 = wr * 8192 + r15 * 64;
    int bbase0 = (wc >> 1) * 8192 + (wc & 1) * 4096 + r15 * 64;

    f32x4 acc[8][4];
    #pragma unroll
    for (int i = 0; i < 8; ++i)
        #pragma unroll
        for (int j = 0; j < 4; ++j) acc[i][j] = (f32x4){0.f, 0.f, 0.f, 0.f};

#define STAGE(buf, kt) do { \
    _Pragma("unroll") \
    for (int i = 0; i < 4; ++i) { \
        gload16(Ob + asrc[i] + (kt) * 64, &AsF[(buf) * BUFE + adoff[i]]); \
        gload16(Wp + bsrc[i] + (kt) * 64, &BsF[(buf) * BUFE + adoff[i]]); \
    } } while (0)

    bf16x8 af[4][2], bw[2][2];
#define PHASE(mh, nh, LA, LB, bo) do { \
    if (LA) { _Pragma("unroll") for (int mi = 0; mi < 4; ++mi) { \
        af[mi][0] = *(const bf16x8*)&AsF[(bo) + abase0 + ((mh)*4+mi)*1024 + sl0*8]; \
        af[mi][1] = *(const bf16x8*)&AsF[(bo) + abase0 + ((mh)*4+mi)*1024 + sl1*8]; } } \
    if (LB) { _Pragma("unroll") for (int ni = 0; ni < 2; ++ni) { \
        bw[ni][0] = *(const bf16x8*)&BsF[(bo) + bbase0 + ((nh)*2+ni)*1024 + sl0*8]; \
        bw[ni][1] = *(const bf16x8*)&BsF[(bo) + bbase0 + ((nh)*2+ni)*1024 + sl1*8]; } } \
    __builtin_amdgcn_s_setprio(1); \
    _Pragma("unroll") for (int mi = 0; mi < 4; ++mi) \
        _Pragma("unroll") for (int ni = 0; ni < 2; ++ni) { \
            acc[(mh)*4+mi][(nh)*2+ni] = MFMA(af[mi][0], bw[ni][0], acc[(mh)*4+mi][(nh)*2+ni]); \
            acc[(mh)*4+mi][(nh)*2+ni] = MFMA(af[mi][1], bw[ni][1], acc[(mh)*4+mi][(nh)*2+ni]); } \
    __builtin_amdgcn_s_setprio(0); \
} while (0)

    STAGE(0, 0);
    STAGE(1, 1);
    asm volatile("s_waitcnt vmcnt(8)" ::: "memory");
    __builtin_amdgcn_s_barrier();

    for (int t = 0; t < NKT; ++t) {
        int bo = (t & 1) * BUFE;
        PHASE(0, 0, 1, 1, bo);
        PHASE(0, 1, 0, 1, bo);
        PHASE(1, 1, 1, 0, bo);
        PHASE(1, 0, 0, 1, bo);
        __builtin_amdgcn_s_barrier();
        if (t + 2 < NKT) {
            STAGE(t & 1, t + 2);
            asm volatile("s_waitcnt vmcnt(8)" ::: "memory");
        } else {
            asm volatile("s_waitcnt vmcnt(0)" ::: "memory");
        }
        __builtin_amdgcn_s_barrier();
    }
#undef STAGE
#undef PHASE

    // epilogue: fp32 out, 64B-contiguous per 16-lane group
    #pragma unroll
    for (int n = 0; n < 4; ++n) {
        int col = n0 + wc * 64 + n * 16 + r15;
        float bv = pbias[col];
        #pragma unroll
        for (int m = 0; m < 8; ++m) {
            #pragma unroll
            for (int r = 0; r < 4; ++r) {
                int row = m0 + wr * 128 + m * 16 + hi * 4 + r;
                if (row < NTOKENS)
                    out[(size_t)row * DIM + col] = acc[m][n][r] + bv;
            }
        }
    }
}

// ---------------- fused attention: QKV[token][2304] in, O[token][768] out
#define KP 72          // Kl pitch (elems)
#define PP 232         // Pl pitch (elems), 464B rows (16B-aligned)
#define VPITCH 256     // VT pitch (elems) = 32 16B-slots

__global__ __launch_bounds__(256, 2) void attn(
    const unsigned short* __restrict__ QKV, const float* __restrict__ biasm,
    unsigned short* __restrict__ O)
{
    __shared__ __attribute__((aligned(16))) unsigned short VT[64 * VPITCH];   // 32768 B
    __shared__ __attribute__((aligned(16))) unsigned short KlPl[208 * KP];    // 29952 B

    int tid = threadIdx.x, lane = tid & 63, wid = tid >> 6;
    int r15 = lane & 15, hi = lane >> 4;
    int wg = blockIdx.x;
    int g = wg >> 5, qt = (wg >> 3) & 3, p = wg & 7;
    int bh = g * 8 + p;
    int h = bh % NHEADS, b = bh / NHEADS;
    size_t tb = (size_t)b * NTOK;
    int hq = h * 64;
    int rbase = qt * 64 + wid * 16 + hi * 4;

    // ---- phase 0 (issue order matters):
    // (a) K loads first -> K ds_writes drain ONLY K (vmcnt counts newest-first)
    int kcol = (tid & 7) * 8;
    bf16x8 kreg[7];
    #pragma unroll
    for (int t = 0; t < 7; ++t) {
        int row = t * 32 + (tid >> 3);
        int rc = row < NTOK ? row : (NTOK - 1);
        kreg[t] = *(const bf16x8*)(QKV + (tb + rc) * CDIM + 768 + hq + kcol);
    }
    #pragma unroll
    for (int t = 0; t < 7; ++t) {
        int row = t * 32 + (tid >> 3);
        if (row < NTOK)
            *(bf16x8*)&KlPl[row * KP + kcol] = kreg[t];
    }

    // (b) V loads into regs (consumed after QK^T)
    bf16x8 v0r[4], v1r[4];
    #pragma unroll
    for (int it = 0; it < 4; ++it) {
        int c = it * 256 + tid;
        int rp = c >> 3, kc = c & 7;
        int r0 = 2 * rp, r1 = 2 * rp + 1;
        bf16x8 z = (bf16x8)(short)0;
        v0r[it] = z; v1r[it] = z;
        if (r0 < NTOK) v0r[it] = *(const bf16x8*)(QKV + (tb + r0) * CDIM + 1536 + hq + kc * 8);
        if (r1 < NTOK) v1r[it] = *(const bf16x8*)(QKV + (tb + r1) * CDIM + 1536 + hq + kc * 8);
    }

    // (c) Q fragments (needed right after barrier)
    int qrow_g = qt * 64 + wid * 16 + r15;
    int qsrc = qrow_g < NTOK ? qrow_g : (NTOK - 1);
    bf16x8 aq[2];
    #pragma unroll
    for (int ks = 0; ks < 2; ++ks)
        aq[ks] = *(const bf16x8*)(QKV + (tb + qsrc) * CDIM + hq + ks * 32 + hi * 8);

    // (d) bias prefetch (f32, consumed in softmax; latency hides under QK^T)
    float breg[4][13];
    {
        const float* bb = biasm + h * NPAIR;
        #pragma unroll
        for (int r = 0; r < 4; ++r) {
            int row_g = rbase + r;
            int rowc = row_g < NTOK ? row_g : (NTOK - 1);
            const float* brow = bb + rowc * NTOK + r15;
            #pragma unroll
            for (int t = 0; t < 13; ++t) {
                int off = t * 16;
                if (t == 12 && r15 >= 5) off = 0;   // col>=197 masked later; stay in-bounds
                breg[r][t] = brow[off];
            }
        }
    }
    __syncthreads();

    // S = Q K^T
    f32x4 sa[13];
    #pragma unroll
    for (int t = 0; t < 13; ++t) sa[t] = (f32x4){0.f,0.f,0.f,0.f};
    __builtin_amdgcn_s_setprio(1);
    #pragma unroll
    for (int t = 0; t < 13; ++t) {
        #pragma unroll
        for (int ks = 0; ks < 2; ++ks) {
            bf16x8 bk = *(bf16x8*)&KlPl[(t * 16 + r15) * KP + ks * 32 + hi * 8];
            sa[t] = MFMA(aq[ks], bk, sa[t]);
        }
    }
    __builtin_amdgcn_s_setprio(0);
    __syncthreads();          // all waves past QK^T: Kl region becomes Pl

    // V regs -> VT (swizzled)
    #pragma unroll
    for (int it = 0; it < 4; ++it) {
        int c = it * 256 + tid;
        int rp = c >> 3, kc = c & 7;
        if (rp < 112) {
            #pragma unroll
            for (int j = 0; j < 8; ++j) {
                unsigned int w = (unsigned int)(unsigned short)v0r[it][j] |
                                 ((unsigned int)(unsigned short)v1r[it][j] << 16);
                int slot2 = (rp >> 2) ^ j ^ kc;
                *(unsigned int*)&VT[(kc * 8 + j) * VPITCH + slot2 * 8 + (rp & 3) * 2] = w;
            }
        }
    }

    // softmax (unnormalized; 1/sum deferred to epilogue) -> P into KlPl region
    int plbase = wid * (16 * PP);
    float invr[4];
    #pragma unroll
    for (int r = 0; r < 4; ++r) {
        #pragma unroll
        for (int t = 0; t < 13; ++t) {
            int col = t * 16 + r15;
            if (col < NTOK) sa[t][r] += breg[r][t];
            else            sa[t][r] = -1e30f;
        }
        float mx = sa[0][r];
        #pragma unroll
        for (int t = 1; t < 13; ++t) mx = fmaxf(mx, sa[t][r]);
        #pragma unroll
        for (int m = 1; m < 16; m <<= 1) mx = fmaxf(mx, __shfl_xor(mx, m));
        float sum = 0.f;
        #pragma unroll
        for (int t = 0; t < 13; ++t) {
            float e = __expf(sa[t][r] - mx);
            sa[t][r] = e; sum += e;
        }
        int roff = plbase + (hi * 4 + r) * PP;
        #pragma unroll
        for (int t = 0; t < 13; ++t)
            KlPl[roff + t * 16 + r15] = f2bf(sa[t][r]);
        KlPl[roff + 208 + r15] = 0;
        #pragma unroll
        for (int m = 1; m < 16; m <<= 1) sum += __shfl_xor(sum, m);
        invr[r] = __builtin_amdgcn_rcpf(sum);
    }
    __syncthreads();          // VT fully written

    // O = P V ; V^T frags via single b128 per (dt,ks) from swizzled VT
    f32x4 oa[4];
    #pragma unroll
    for (int dt = 0; dt < 4; ++dt) oa[dt] = (f32x4){0.f,0.f,0.f,0.f};
    int X = hi ^ (r15 & 7) ^ (r15 >> 3);
    __builtin_amdgcn_s_setprio(1);
    #pragma unroll
    for (int ks = 0; ks < 7; ++ks) {
        bf16x8 ap = *(bf16x8*)&KlPl[plbase + r15 * PP + ks * 32 + hi * 8];
        #pragma unroll
        for (int dt = 0; dt < 4; ++dt) {
            int d = dt * 16 + r15;
            int slotp = (ks * 4) ^ (dt * 2) ^ X;
            bf16x8 bv = *(bf16x8*)&VT[d * VPITCH + slotp * 8];
            oa[dt] = MFMA(ap, bv, oa[dt]);
        }
    }
    __builtin_amdgcn_s_setprio(0);

    // O write: scale by 1/sum, per-wave LDS transpose -> 16B stores
    #pragma unroll
    for (int dt = 0; dt < 4; ++dt)
        #pragma unroll
        for (int r = 0; r < 4; ++r)
            KlPl[plbase + (hi * 4 + r) * 72 + dt * 16 + r15] = f2bf(oa[dt][r] * invr[r]);
    #pragma unroll
    for (int it = 0; it < 2; ++it) {
        int c = it * 64 + lane;
        int lr = c >> 3, cc = c & 7;
        int qrow = qt * 64 + wid * 16 + lr;
        if (qrow < NTOK)
            *(bf16x8*)(O + (tb + qrow) * DIM + hq + cc * 8) =
                *(bf16x8*)&KlPl[plbase + lr * 72 + cc * 8];
    }
}

extern "C" void kernel_launch(void* const* d_in, const int* in_sizes, int n_in,
                              void* d_out, int out_size, void* d_ws, size_t ws_size,
                              hipStream_t stream) {
    const float* x      = (const float*)d_in[0];
    const float* qkv_w  = (const float*)d_in[1];
    const float* q_bias = (const float*)d_in[2];
    const float* v_bias = (const float*)d_in[3];
    const float* rpb    = (const float*)d_in[4];
    const float* proj_w = (const float*)d_in[5];
    const float* proj_b = (const float*)d_in[6];
    const int*   rel    = (const int*)d_in[7];
    float* out = (float*)d_out;

    const size_t NELEM = (size_t)NTOKENS * DIM;      // 9,682,944
    const size_t WQKV  = (size_t)3 * DIM * DIM;
    const size_t WPROJ = (size_t)DIM * DIM;
    unsigned short* Xb   = (unsigned short*)d_ws;    // reused as Ob after gemm_qkv8
    unsigned short* Wqb  = Xb + NELEM;
    unsigned short* Wpb  = Wqb + WQKV;
    unsigned short* QKVb = Wpb + WPROJ;              // [12608][2304]
    float* biasm = (float*)(QKVb + (size_t)NTOKENS * CDIM);  // f32 [12][197][197]
    unsigned short* Ob = Xb;

    prep<<<NB_X + NB_WQ + NB_WP + NB_BIAS, 256, 0, stream>>>(
        x, qkv_w, proj_w, rpb, rel, Xb, Wqb, Wpb, biasm);

    gemm_qkv8<<<450, 512, 0, stream>>>(Xb, Wqb, q_bias, v_bias, QKVb);

    attn<<<3072, 256, 0, stream>>>(QKVb, biasm, Ob);

    gemm_proj8<<<150, 512, 0, stream>>>(Ob, Wpb, proj_b, out);
}